// Round 3
// baseline (322.783 us; speedup 1.0000x reference)
//
#include <hip/hip_runtime.h>
#include <hip/hip_fp16.h>
#include <math.h>

#define N_NODES 100000
#define N_EDGES 1600000
#define IN_FEAT 128
#define HIDDEN 64
#define N_CLASSES 16

#define TM 64
#define GBLK ((N_NODES + TM - 1) / TM)  // 1563

#define NBUK 196                        // buckets of 512 nodes (dst>>9)
#define CB 4096                         // edges per coarse block
#define NCB ((N_EDGES + CB - 1) / CB)   // 391
#define EPB 1024                        // edges per bukhist block
#define NHB ((N_EDGES + EPB - 1) / EPB) // 1563

// ---------------- bucket histogram (LDS, tiny global flush) ----------------

__global__ void zero_buk_k(int* __restrict__ buk_cnt) {
    if (threadIdx.x < NBUK + 4) buk_cnt[threadIdx.x] = 0;
}

__global__ __launch_bounds__(256) void bukhist_k(const int* __restrict__ dst,
                                                 int* __restrict__ buk_cnt) {
    __shared__ int hist[NBUK + 4];
    int tid = threadIdx.x;
    if (tid < NBUK) hist[tid] = 0;
    __syncthreads();
    int base = blockIdx.x * EPB + tid * 4;
    if (base < N_EDGES) {  // N_EDGES % 4 == 0
        int4 d4 = ((const int4*)dst)[base >> 2];
        atomicAdd(&hist[d4.x >> 9], 1);
        atomicAdd(&hist[d4.y >> 9], 1);
        atomicAdd(&hist[d4.z >> 9], 1);
        atomicAdd(&hist[d4.w >> 9], 1);
    }
    __syncthreads();
    if (tid < NBUK && hist[tid] != 0) atomicAdd(&buk_cnt[tid], hist[tid]);
}

// scan 196 bucket counts -> buk_off (exclusive), init bcur
__global__ __launch_bounds__(256) void buk_scan_k(const int* __restrict__ buk_cnt,
                                                  int* __restrict__ buk_off,
                                                  int* __restrict__ bcur) {
    __shared__ int sm[256];
    int t = threadIdx.x;
    int v = (t < NBUK) ? buk_cnt[t] : 0;
    sm[t] = v;
    __syncthreads();
    for (int s = 1; s < 256; s <<= 1) {
        int add = (t >= s) ? sm[t - s] : 0;
        __syncthreads();
        sm[t] += add;
        __syncthreads();
    }
    if (t < NBUK) {
        int excl = sm[t] - v;
        buk_off[t] = excl;
        bcur[t] = excl;
    }
    if (t == 0) buk_off[NBUK] = N_EDGES;
}

// ---------------- coarse partition: group edges by 512-node bucket ----------------

__global__ __launch_bounds__(256) void coarse_k(const int* __restrict__ src,
                                                const int* __restrict__ dst,
                                                int* __restrict__ bcur,
                                                int2* __restrict__ pairs) {
    __shared__ int hist[NBUK + 4], loff[NBUK + 4], cur[NBUK + 4], gbase[NBUK + 4];
    __shared__ int sc[256];
    __shared__ int2 stage[CB];  // 32 KB
    int tid = threadIdx.x;
    int eb = blockIdx.x * CB;
    int nvalid = N_EDGES - eb;
    if (nvalid > CB) nvalid = CB;

    if (tid < NBUK) hist[tid] = 0;
    __syncthreads();

    int4 s4[4], d4[4];
    #pragma unroll
    for (int q = 0; q < 4; ++q) {
        int e4 = (eb >> 2) + tid + q * 256;
        if (e4 * 4 < N_EDGES) {
            s4[q] = ((const int4*)src)[e4];
            d4[q] = ((const int4*)dst)[e4];
        } else {
            d4[q] = make_int4(-1, -1, -1, -1);
            s4[q] = make_int4(0, 0, 0, 0);
        }
    }
    #pragma unroll
    for (int q = 0; q < 4; ++q) {
        if (d4[q].x >= 0) {
            atomicAdd(&hist[d4[q].x >> 9], 1);
            atomicAdd(&hist[d4[q].y >> 9], 1);
            atomicAdd(&hist[d4[q].z >> 9], 1);
            atomicAdd(&hist[d4[q].w >> 9], 1);
        }
    }
    __syncthreads();

    int v = (tid < NBUK) ? hist[tid] : 0;
    sc[tid] = v;
    __syncthreads();
    for (int s = 1; s < 256; s <<= 1) {
        int add = (tid >= s) ? sc[tid - s] : 0;
        __syncthreads();
        sc[tid] += add;
        __syncthreads();
    }
    if (tid < NBUK) {
        int excl = sc[tid] - v;
        loff[tid] = excl;
        cur[tid] = excl;
        gbase[tid] = atomicAdd(&bcur[tid], v);
    }
    __syncthreads();

    #pragma unroll
    for (int q = 0; q < 4; ++q) {
        if (d4[q].x >= 0) {
            int b, r;
            b = d4[q].x >> 9; r = atomicAdd(&cur[b], 1); stage[r] = make_int2(s4[q].x, d4[q].x);
            b = d4[q].y >> 9; r = atomicAdd(&cur[b], 1); stage[r] = make_int2(s4[q].y, d4[q].y);
            b = d4[q].z >> 9; r = atomicAdd(&cur[b], 1); stage[r] = make_int2(s4[q].z, d4[q].z);
            b = d4[q].w >> 9; r = atomicAdd(&cur[b], 1); stage[r] = make_int2(s4[q].w, d4[q].w);
        }
    }
    __syncthreads();

    for (int i = tid; i < nvalid; i += 256) {
        int2 p = stage[i];
        int b = p.y >> 9;
        pairs[gbase[b] + (i - loff[b])] = p;
    }
}

// ---------------- fine: per-bucket degree count (LDS) + dinv + row_ptr + placement ----------------

__global__ __launch_bounds__(256) void fine2_k(const int2* __restrict__ pairs,
                                               const int* __restrict__ buk_off,
                                               int* __restrict__ csr_src,
                                               int* __restrict__ row_ptr,
                                               float* __restrict__ dinv) {
    __shared__ int cnt[512];
    __shared__ int psc[256];
    __shared__ int cur[512];
    int b = blockIdx.x;
    int node0 = b * 512;
    int nn = N_NODES - node0;
    if (nn > 512) nn = 512;
    int tid = threadIdx.x;

    cnt[tid] = 0; cnt[tid + 256] = 0;
    __syncthreads();

    int e0 = buk_off[b];
    int e1 = buk_off[b + 1];

    for (int e = e0 + tid; e < e1; e += 256)
        atomicAdd(&cnt[pairs[e].y - node0], 1);
    __syncthreads();

    int c0 = cnt[2 * tid], c1 = cnt[2 * tid + 1];
    int p = c0 + c1;
    psc[tid] = p;
    __syncthreads();
    for (int s = 1; s < 256; s <<= 1) {
        int add = (tid >= s) ? psc[tid - s] : 0;
        __syncthreads();
        psc[tid] += add;
        __syncthreads();
    }
    int excl = psc[tid] - p;
    int g0 = e0 + excl;
    int g1 = g0 + c0;
    cur[2 * tid] = g0;
    cur[2 * tid + 1] = g1;
    if (2 * tid < nn) {
        row_ptr[node0 + 2 * tid] = g0;
        dinv[node0 + 2 * tid] = 1.0f / sqrtf((float)(c0 + 1));
    }
    if (2 * tid + 1 < nn) {
        row_ptr[node0 + 2 * tid + 1] = g1;
        dinv[node0 + 2 * tid + 1] = 1.0f / sqrtf((float)(c1 + 1));
    }
    if (b == NBUK - 1 && tid == 0) row_ptr[N_NODES] = N_EDGES;
    __syncthreads();

    for (int e = e0 + tid; e < e1; e += 256) {
        int2 pr = pairs[e];
        int pos = atomicAdd(&cur[pr.y - node0], 1);
        csr_src[pos] = pr.x;
    }
}

// ---------------- register-tiled GEMM 1: hws_h = fp16((x @ W1) * dinv[row]) ----------------

__global__ __launch_bounds__(256) void gemm1_tiled_k(const float* __restrict__ x,
                                                     const float* __restrict__ W,
                                                     const float* __restrict__ dinv,
                                                     __half* __restrict__ hws_h) {
    __shared__ float Ws[64][64];
    __shared__ float xt[64][68];
    int tid = threadIdx.x;
    int row0 = blockIdx.x * TM;
    int rgrp4 = (tid >> 4) * 4;
    int cgrp4 = (tid & 15) * 4;

    float acc[4][4];
    #pragma unroll
    for (int r = 0; r < 4; ++r)
        #pragma unroll
        for (int c = 0; c < 4; ++c) acc[r][c] = 0.0f;

    for (int k0 = 0; k0 < IN_FEAT; k0 += 64) {
        #pragma unroll
        for (int i = 0; i < 4; ++i) {
            int f4 = tid + i * 256;
            int kk = f4 >> 4, c4 = (f4 & 15) * 4;
            *(float4*)&Ws[kk][c4] = *(const float4*)&W[(size_t)(k0 + kk) * HIDDEN + c4];
        }
        #pragma unroll
        for (int i = 0; i < 4; ++i) {
            int f4 = tid + i * 256;
            int rr = f4 >> 4, kq = (f4 & 15) * 4;
            int row = row0 + rr;
            if (row >= N_NODES) row = N_NODES - 1;
            float4 v = *(const float4*)&x[(size_t)row * IN_FEAT + k0 + kq];
            xt[kq + 0][rr] = v.x; xt[kq + 1][rr] = v.y;
            xt[kq + 2][rr] = v.z; xt[kq + 3][rr] = v.w;
        }
        __syncthreads();

        #pragma unroll 16
        for (int kk = 0; kk < 64; ++kk) {
            float4 a = *(const float4*)&xt[kk][rgrp4];
            float4 b = *(const float4*)&Ws[kk][cgrp4];
            acc[0][0] += a.x * b.x; acc[0][1] += a.x * b.y; acc[0][2] += a.x * b.z; acc[0][3] += a.x * b.w;
            acc[1][0] += a.y * b.x; acc[1][1] += a.y * b.y; acc[1][2] += a.y * b.z; acc[1][3] += a.y * b.w;
            acc[2][0] += a.z * b.x; acc[2][1] += a.z * b.y; acc[2][2] += a.z * b.z; acc[2][3] += a.z * b.w;
            acc[3][0] += a.w * b.x; acc[3][1] += a.w * b.y; acc[3][2] += a.w * b.z; acc[3][3] += a.w * b.w;
        }
        __syncthreads();
    }

    #pragma unroll
    for (int r = 0; r < 4; ++r) {
        int row = row0 + rgrp4 + r;
        if (row < N_NODES) {
            float dn = dinv[row];
            __half2* ph = (__half2*)&hws_h[(size_t)row * HIDDEN + cgrp4];
            ph[0] = __floats2half2_rn(acc[r][0] * dn, acc[r][1] * dn);
            ph[1] = __floats2half2_rn(acc[r][2] * dn, acc[r][3] * dn);
        }
    }
}

// ---------------- register-tiled GEMM 2: hws_h = fp16((relu(agg) @ W2) * dinv[row]) ----------------

__global__ __launch_bounds__(256) void gemm2_tiled_k(const float* __restrict__ agg,
                                                     const float* __restrict__ W,
                                                     const float* __restrict__ dinv,
                                                     __half* __restrict__ hws_h) {
    __shared__ float Ws[64][64];
    __shared__ float xt[64][68];
    int tid = threadIdx.x;
    int row0 = blockIdx.x * TM;
    int rgrp4 = (tid >> 4) * 4;
    int cgrp4 = (tid & 15) * 4;

    #pragma unroll
    for (int i = 0; i < 4; ++i) {
        int f4 = tid + i * 256;
        int kk = f4 >> 4, c4 = (f4 & 15) * 4;
        *(float4*)&Ws[kk][c4] = *(const float4*)&W[(size_t)kk * HIDDEN + c4];
    }
    #pragma unroll
    for (int i = 0; i < 4; ++i) {
        int f4 = tid + i * 256;
        int rr = f4 >> 4, kq = (f4 & 15) * 4;
        int row = row0 + rr;
        if (row >= N_NODES) row = N_NODES - 1;
        float4 v = *(const float4*)&agg[(size_t)row * HIDDEN + kq];
        xt[kq + 0][rr] = fmaxf(v.x, 0.f); xt[kq + 1][rr] = fmaxf(v.y, 0.f);
        xt[kq + 2][rr] = fmaxf(v.z, 0.f); xt[kq + 3][rr] = fmaxf(v.w, 0.f);
    }
    __syncthreads();

    float acc[4][4];
    #pragma unroll
    for (int r = 0; r < 4; ++r)
        #pragma unroll
        for (int c = 0; c < 4; ++c) acc[r][c] = 0.0f;

    #pragma unroll 16
    for (int kk = 0; kk < 64; ++kk) {
        float4 a = *(const float4*)&xt[kk][rgrp4];
        float4 b = *(const float4*)&Ws[kk][cgrp4];
        acc[0][0] += a.x * b.x; acc[0][1] += a.x * b.y; acc[0][2] += a.x * b.z; acc[0][3] += a.x * b.w;
        acc[1][0] += a.y * b.x; acc[1][1] += a.y * b.y; acc[1][2] += a.y * b.z; acc[1][3] += a.y * b.w;
        acc[2][0] += a.z * b.x; acc[2][1] += a.z * b.y; acc[2][2] += a.z * b.z; acc[2][3] += a.z * b.w;
        acc[3][0] += a.w * b.x; acc[3][1] += a.w * b.y; acc[3][2] += a.w * b.z; acc[3][3] += a.w * b.w;
    }

    #pragma unroll
    for (int r = 0; r < 4; ++r) {
        int row = row0 + rgrp4 + r;
        if (row < N_NODES) {
            float dn = dinv[row];
            __half2* ph = (__half2*)&hws_h[(size_t)row * HIDDEN + cgrp4];
            ph[0] = __floats2half2_rn(acc[r][0] * dn, acc[r][1] * dn);
            ph[1] = __floats2half2_rn(acc[r][2] * dn, acc[r][3] * dn);
        }
    }
}

// ---------------- CSR pull: agg[d] = b + dinv[d]*(hws[d] + sum_in hws[s]) ----------------
// one wave per node, lane = channel, fp16 rows.
//
// KEY CHANGE (this round): uniform-base addressing for the gathers. Round-1 code
// computed hws_h[(s<<6)+lane] — mixing the uniform row index s with the divergent
// lane inside the index forced a per-lane 64-bit VGPR address (v_lshlrev +
// v_add_co + v_addc per edge -> ~8 VALU/edge -> VALUBusy 60%). Now the row base
// pointer (hws_h + (size_t)s<<6) is computed from the readlane result, which the
// compiler knows is uniform -> 3 SALU on the scalar pipe, and the load becomes
// global_load_ushort v, v_laneoff, s[base] with a LOOP-INVARIANT voffset.
// Per-edge VALU: readlane + cvt + fmac = 3.

__global__ __launch_bounds__(256) void pull_k(const int* __restrict__ row_ptr,
                                              const int* __restrict__ csr_src,
                                              const float* __restrict__ dinv,
                                              const __half* __restrict__ hws_h,
                                              const float* __restrict__ b,
                                              float* __restrict__ agg) {
    // wave-uniform by construction: blockIdx.x*4 + waveId
    int node = __builtin_amdgcn_readfirstlane((blockIdx.x * 256 + threadIdx.x) >> 6);
    int lane = threadIdx.x & 63;
    if (node >= N_NODES) return;   // uniform -> scalar branch

    int start = __builtin_amdgcn_readfirstlane(row_ptr[node]);
    int end   = __builtin_amdgcn_readfirstlane(row_ptr[node + 1]);

    // independent loads issued early: bias, self row (uniform base), dinv
    const __half* __restrict__ selfrow = hws_h + ((size_t)node << 6);
    float blane = b[lane];
    float a0 = __half2float(selfrow[lane]);   // self-loop term
    float dn = dinv[node];

    float a1 = 0.f, a2 = 0.f, a3 = 0.f, a4 = 0.f, a5 = 0.f, a6 = 0.f, a7 = 0.f;

    int base = start;
    while (base < end) {                       // one pass for deg<=64 (virtually always)
        int rem = end - base;                  // uniform
        int ci = base + lane;
        int lastci = end - 1;
        if (ci > lastci) ci = lastci;          // clamp into valid range (same cacheline)
        int idxv = csr_src[ci];                // ONE coalesced load: up to 64 indices
        int nch = rem < 64 ? rem : 64;

        for (int j = 0; j < nch; j += 16) {    // 16 gathers in flight per wait
            #pragma unroll
            for (int k = 0; k < 16; ++k) {
                int jj = j + k;                                    // uniform
                int s = __builtin_amdgcn_readlane(idxv, jj);       // SGPR broadcast
                const __half* __restrict__ row = hws_h + ((size_t)s << 6);  // SALU base
                float w = (jj < rem) ? 1.f : 0.f;                  // uniform pad weight
                float v = __half2float(row[lane]);                 // saddr + lane voffset
                if (k == 0)      a0 += w * v;
                else if (k == 1) a1 += w * v;
                else if (k == 2) a2 += w * v;
                else if (k == 3) a3 += w * v;
                else if (k == 4) a4 += w * v;
                else if (k == 5) a5 += w * v;
                else if (k == 6) a6 += w * v;
                else if (k == 7) a7 += w * v;
                else if (k == 8)  a0 += w * v;
                else if (k == 9)  a1 += w * v;
                else if (k == 10) a2 += w * v;
                else if (k == 11) a3 += w * v;
                else if (k == 12) a4 += w * v;
                else if (k == 13) a5 += w * v;
                else if (k == 14) a6 += w * v;
                else              a7 += w * v;
            }
        }
        base += 64;
    }

    float sum = ((a0 + a1) + (a2 + a3)) + ((a4 + a5) + (a6 + a7));
    float* __restrict__ outrow = agg + ((size_t)node << 6);   // uniform base
    outrow[lane] = blane + dn * sum;
}

// ---------------- final: out = relu(agg) @ Wl + bl ----------------

__global__ __launch_bounds__(256) void final_k(const float* __restrict__ agg,
                                               const float* __restrict__ Wl,
                                               const float* __restrict__ bl,
                                               float* __restrict__ out) {
    __shared__ float Ws[HIDDEN * N_CLASSES];
    __shared__ float hs[16][HIDDEN + 1];
    int tid = threadIdx.x;

    if (tid < HIDDEN * N_CLASSES / 4) ((float4*)Ws)[tid] = ((const float4*)Wl)[tid];

    int row0 = blockIdx.x * 16;
    for (int i = tid; i < 16 * HIDDEN; i += 256) {
        int rr = i >> 6;
        int kk = i & 63;
        hs[rr][kk] = fmaxf(agg[(size_t)(row0 + rr) * HIDDEN + kk], 0.0f);
    }
    __syncthreads();

    int col = tid & 15;
    int r = tid >> 4;
    float acc = bl[col];
    #pragma unroll
    for (int k = 0; k < HIDDEN; ++k)
        acc += hs[r][k] * Ws[k * N_CLASSES + col];
    out[(size_t)(row0 + r) * N_CLASSES + col] = acc;
}

// ---------------- launch ----------------

extern "C" void kernel_launch(void* const* d_in, const int* in_sizes, int n_in,
                              void* d_out, int out_size, void* d_ws, size_t ws_size,
                              hipStream_t stream) {
    const float* x  = (const float*)d_in[0];
    const int*   ei = (const int*)d_in[1];
    const float* W1 = (const float*)d_in[2];
    const float* b1 = (const float*)d_in[3];
    const float* W2 = (const float*)d_in[4];
    const float* b2 = (const float*)d_in[5];
    const float* Wl = (const float*)d_in[6];
    const float* bl = (const float*)d_in[7];
    float* out = (float*)d_out;

    const int* src = ei;
    const int* dst = ei + N_EDGES;

    __half* hws_h  = (__half*)d_ws;                              // N*64 halves (12.8 MB)
    float* agg     = (float*)(hws_h + (size_t)N_NODES * HIDDEN); // N*64 floats (25.6 MB)
    int2*  pairs   = (int2*)agg;                                 // aliases agg (dead before pull writes agg)
    int*   csr_src = (int*)(agg + (size_t)N_NODES * HIDDEN);     // E
    float* dinv    = (float*)(csr_src + N_EDGES);                // N
    int*   row_ptr = (int*)(dinv + N_NODES);                     // N+4
    int*   buk_cnt = row_ptr + N_NODES + 4;                      // 200
    int*   buk_off = buk_cnt + 200;                              // 200
    int*   bcur    = buk_off + 200;                              // 200

    // --- CSR build (degree counting confined to LDS) ---
    zero_buk_k<<<1, 256, 0, stream>>>(buk_cnt);
    bukhist_k<<<NHB, 256, 0, stream>>>(dst, buk_cnt);
    buk_scan_k<<<1, 256, 0, stream>>>(buk_cnt, buk_off, bcur);
    coarse_k<<<NCB, 256, 0, stream>>>(src, dst, bcur, pairs);
    fine2_k<<<NBUK, 256, 0, stream>>>(pairs, buk_off, csr_src, row_ptr, dinv);

    // --- layer 1 ---
    gemm1_tiled_k<<<GBLK, 256, 0, stream>>>(x, W1, dinv, hws_h);
    pull_k<<<(N_NODES * 64 + 255) / 256, 256, 0, stream>>>(row_ptr, csr_src, dinv,
                                                           hws_h, b1, agg);

    // --- layer 2 ---
    gemm2_tiled_k<<<GBLK, 256, 0, stream>>>(agg, W2, dinv, hws_h);
    pull_k<<<(N_NODES * 64 + 255) / 256, 256, 0, stream>>>(row_ptr, csr_src, dinv,
                                                           hws_h, b2, agg);

    // --- classifier head ---
    final_k<<<N_NODES / 16, 256, 0, stream>>>(agg, Wl, bl, out);
}

// Round 4
// 289.666 us; speedup vs baseline: 1.1143x; 1.1143x over previous
//
#include <hip/hip_runtime.h>
#include <hip/hip_fp16.h>
#include <math.h>

#define N_NODES 100000
#define N_EDGES 1600000
#define IN_FEAT 128
#define HIDDEN 64
#define N_CLASSES 16

#define TM 64
#define GBLK ((N_NODES + TM - 1) / TM)  // 1563

#define NBUK 196                        // buckets of 512 nodes (dst>>9)
#define CB 4096                         // edges per coarse block
#define NCB ((N_EDGES + CB - 1) / CB)   // 391
#define NHB 128                         // bukhist blocks (grid-stride) — short atomic chains

// ---------------- bucket histogram (LDS, tiny global flush) ----------------

__global__ void zero_buk_k(int* __restrict__ buk_cnt) {
    if (threadIdx.x < NBUK + 4) buk_cnt[threadIdx.x] = 0;
}

// KEY CHANGE (this round): 1563 blocks -> 128 grid-stride blocks.
// The old epilogue had 1563 blocks atomicAdd-ing into the SAME 196 global
// counters: 196 parallel chains x 1563 serialized same-address atomics
// (~28ns each) = the whole observed 44us (HBM 1.3%, VALUBusy 0.3%).
// 128 blocks -> chain length 128 -> ~4us, LDS histogram work still trivial.
__global__ __launch_bounds__(256) void bukhist_k(const int* __restrict__ dst,
                                                 int* __restrict__ buk_cnt) {
    __shared__ int hist[NBUK + 4];
    int tid = threadIdx.x;
    if (tid < NBUK) hist[tid] = 0;
    __syncthreads();
    const int n4 = N_EDGES >> 2;   // N_EDGES % 4 == 0
    for (int i4 = blockIdx.x * 256 + tid; i4 < n4; i4 += NHB * 256) {
        int4 d4 = ((const int4*)dst)[i4];
        atomicAdd(&hist[d4.x >> 9], 1);
        atomicAdd(&hist[d4.y >> 9], 1);
        atomicAdd(&hist[d4.z >> 9], 1);
        atomicAdd(&hist[d4.w >> 9], 1);
    }
    __syncthreads();
    if (tid < NBUK && hist[tid] != 0) atomicAdd(&buk_cnt[tid], hist[tid]);
}

// scan 196 bucket counts -> buk_off (exclusive), init bcur
__global__ __launch_bounds__(256) void buk_scan_k(const int* __restrict__ buk_cnt,
                                                  int* __restrict__ buk_off,
                                                  int* __restrict__ bcur) {
    __shared__ int sm[256];
    int t = threadIdx.x;
    int v = (t < NBUK) ? buk_cnt[t] : 0;
    sm[t] = v;
    __syncthreads();
    for (int s = 1; s < 256; s <<= 1) {
        int add = (t >= s) ? sm[t - s] : 0;
        __syncthreads();
        sm[t] += add;
        __syncthreads();
    }
    if (t < NBUK) {
        int excl = sm[t] - v;
        buk_off[t] = excl;
        bcur[t] = excl;
    }
    if (t == 0) buk_off[NBUK] = N_EDGES;
}

// ---------------- coarse partition: group edges by 512-node bucket ----------------

__global__ __launch_bounds__(256) void coarse_k(const int* __restrict__ src,
                                                const int* __restrict__ dst,
                                                int* __restrict__ bcur,
                                                int2* __restrict__ pairs) {
    __shared__ int hist[NBUK + 4], loff[NBUK + 4], cur[NBUK + 4], gbase[NBUK + 4];
    __shared__ int sc[256];
    __shared__ int2 stage[CB];  // 32 KB
    int tid = threadIdx.x;
    int eb = blockIdx.x * CB;
    int nvalid = N_EDGES - eb;
    if (nvalid > CB) nvalid = CB;

    if (tid < NBUK) hist[tid] = 0;
    __syncthreads();

    int4 s4[4], d4[4];
    #pragma unroll
    for (int q = 0; q < 4; ++q) {
        int e4 = (eb >> 2) + tid + q * 256;
        if (e4 * 4 < N_EDGES) {
            s4[q] = ((const int4*)src)[e4];
            d4[q] = ((const int4*)dst)[e4];
        } else {
            d4[q] = make_int4(-1, -1, -1, -1);
            s4[q] = make_int4(0, 0, 0, 0);
        }
    }
    #pragma unroll
    for (int q = 0; q < 4; ++q) {
        if (d4[q].x >= 0) {
            atomicAdd(&hist[d4[q].x >> 9], 1);
            atomicAdd(&hist[d4[q].y >> 9], 1);
            atomicAdd(&hist[d4[q].z >> 9], 1);
            atomicAdd(&hist[d4[q].w >> 9], 1);
        }
    }
    __syncthreads();

    int v = (tid < NBUK) ? hist[tid] : 0;
    sc[tid] = v;
    __syncthreads();
    for (int s = 1; s < 256; s <<= 1) {
        int add = (tid >= s) ? sc[tid - s] : 0;
        __syncthreads();
        sc[tid] += add;
        __syncthreads();
    }
    if (tid < NBUK) {
        int excl = sc[tid] - v;
        loff[tid] = excl;
        cur[tid] = excl;
        gbase[tid] = atomicAdd(&bcur[tid], v);
    }
    __syncthreads();

    #pragma unroll
    for (int q = 0; q < 4; ++q) {
        if (d4[q].x >= 0) {
            int b, r;
            b = d4[q].x >> 9; r = atomicAdd(&cur[b], 1); stage[r] = make_int2(s4[q].x, d4[q].x);
            b = d4[q].y >> 9; r = atomicAdd(&cur[b], 1); stage[r] = make_int2(s4[q].y, d4[q].y);
            b = d4[q].z >> 9; r = atomicAdd(&cur[b], 1); stage[r] = make_int2(s4[q].z, d4[q].z);
            b = d4[q].w >> 9; r = atomicAdd(&cur[b], 1); stage[r] = make_int2(s4[q].w, d4[q].w);
        }
    }
    __syncthreads();

    for (int i = tid; i < nvalid; i += 256) {
        int2 p = stage[i];
        int b = p.y >> 9;
        pairs[gbase[b] + (i - loff[b])] = p;
    }
}

// ---------------- fine: per-bucket degree count (LDS) + dinv + row_ptr + placement ----------------

__global__ __launch_bounds__(256) void fine2_k(const int2* __restrict__ pairs,
                                               const int* __restrict__ buk_off,
                                               int* __restrict__ csr_src,
                                               int* __restrict__ row_ptr,
                                               float* __restrict__ dinv) {
    __shared__ int cnt[512];
    __shared__ int psc[256];
    __shared__ int cur[512];
    int b = blockIdx.x;
    int node0 = b * 512;
    int nn = N_NODES - node0;
    if (nn > 512) nn = 512;
    int tid = threadIdx.x;

    cnt[tid] = 0; cnt[tid + 256] = 0;
    __syncthreads();

    int e0 = buk_off[b];
    int e1 = buk_off[b + 1];

    for (int e = e0 + tid; e < e1; e += 256)
        atomicAdd(&cnt[pairs[e].y - node0], 1);
    __syncthreads();

    int c0 = cnt[2 * tid], c1 = cnt[2 * tid + 1];
    int p = c0 + c1;
    psc[tid] = p;
    __syncthreads();
    for (int s = 1; s < 256; s <<= 1) {
        int add = (tid >= s) ? psc[tid - s] : 0;
        __syncthreads();
        psc[tid] += add;
        __syncthreads();
    }
    int excl = psc[tid] - p;
    int g0 = e0 + excl;
    int g1 = g0 + c0;
    cur[2 * tid] = g0;
    cur[2 * tid + 1] = g1;
    if (2 * tid < nn) {
        row_ptr[node0 + 2 * tid] = g0;
        dinv[node0 + 2 * tid] = 1.0f / sqrtf((float)(c0 + 1));
    }
    if (2 * tid + 1 < nn) {
        row_ptr[node0 + 2 * tid + 1] = g1;
        dinv[node0 + 2 * tid + 1] = 1.0f / sqrtf((float)(c1 + 1));
    }
    if (b == NBUK - 1 && tid == 0) row_ptr[N_NODES] = N_EDGES;
    __syncthreads();

    for (int e = e0 + tid; e < e1; e += 256) {
        int2 pr = pairs[e];
        int pos = atomicAdd(&cur[pr.y - node0], 1);
        csr_src[pos] = pr.x;
    }
}

// ---------------- register-tiled GEMM 1: hws_h = fp16((x @ W1) * dinv[row]) ----------------

__global__ __launch_bounds__(256) void gemm1_tiled_k(const float* __restrict__ x,
                                                     const float* __restrict__ W,
                                                     const float* __restrict__ dinv,
                                                     __half* __restrict__ hws_h) {
    __shared__ float Ws[64][64];
    __shared__ float xt[64][68];
    int tid = threadIdx.x;
    int row0 = blockIdx.x * TM;
    int rgrp4 = (tid >> 4) * 4;
    int cgrp4 = (tid & 15) * 4;

    float acc[4][4];
    #pragma unroll
    for (int r = 0; r < 4; ++r)
        #pragma unroll
        for (int c = 0; c < 4; ++c) acc[r][c] = 0.0f;

    for (int k0 = 0; k0 < IN_FEAT; k0 += 64) {
        #pragma unroll
        for (int i = 0; i < 4; ++i) {
            int f4 = tid + i * 256;
            int kk = f4 >> 4, c4 = (f4 & 15) * 4;
            *(float4*)&Ws[kk][c4] = *(const float4*)&W[(size_t)(k0 + kk) * HIDDEN + c4];
        }
        #pragma unroll
        for (int i = 0; i < 4; ++i) {
            int f4 = tid + i * 256;
            int rr = f4 >> 4, kq = (f4 & 15) * 4;
            int row = row0 + rr;
            if (row >= N_NODES) row = N_NODES - 1;
            float4 v = *(const float4*)&x[(size_t)row * IN_FEAT + k0 + kq];
            xt[kq + 0][rr] = v.x; xt[kq + 1][rr] = v.y;
            xt[kq + 2][rr] = v.z; xt[kq + 3][rr] = v.w;
        }
        __syncthreads();

        #pragma unroll 16
        for (int kk = 0; kk < 64; ++kk) {
            float4 a = *(const float4*)&xt[kk][rgrp4];
            float4 b = *(const float4*)&Ws[kk][cgrp4];
            acc[0][0] += a.x * b.x; acc[0][1] += a.x * b.y; acc[0][2] += a.x * b.z; acc[0][3] += a.x * b.w;
            acc[1][0] += a.y * b.x; acc[1][1] += a.y * b.y; acc[1][2] += a.y * b.z; acc[1][3] += a.y * b.w;
            acc[2][0] += a.z * b.x; acc[2][1] += a.z * b.y; acc[2][2] += a.z * b.z; acc[2][3] += a.z * b.w;
            acc[3][0] += a.w * b.x; acc[3][1] += a.w * b.y; acc[3][2] += a.w * b.z; acc[3][3] += a.w * b.w;
        }
        __syncthreads();
    }

    #pragma unroll
    for (int r = 0; r < 4; ++r) {
        int row = row0 + rgrp4 + r;
        if (row < N_NODES) {
            float dn = dinv[row];
            __half2* ph = (__half2*)&hws_h[(size_t)row * HIDDEN + cgrp4];
            ph[0] = __floats2half2_rn(acc[r][0] * dn, acc[r][1] * dn);
            ph[1] = __floats2half2_rn(acc[r][2] * dn, acc[r][3] * dn);
        }
    }
}

// ---------------- register-tiled GEMM 2: hws_h = fp16((relu(agg) @ W2) * dinv[row]) ----------------

__global__ __launch_bounds__(256) void gemm2_tiled_k(const float* __restrict__ agg,
                                                     const float* __restrict__ W,
                                                     const float* __restrict__ dinv,
                                                     __half* __restrict__ hws_h) {
    __shared__ float Ws[64][64];
    __shared__ float xt[64][68];
    int tid = threadIdx.x;
    int row0 = blockIdx.x * TM;
    int rgrp4 = (tid >> 4) * 4;
    int cgrp4 = (tid & 15) * 4;

    #pragma unroll
    for (int i = 0; i < 4; ++i) {
        int f4 = tid + i * 256;
        int kk = f4 >> 4, c4 = (f4 & 15) * 4;
        *(float4*)&Ws[kk][c4] = *(const float4*)&W[(size_t)kk * HIDDEN + c4];
    }
    #pragma unroll
    for (int i = 0; i < 4; ++i) {
        int f4 = tid + i * 256;
        int rr = f4 >> 4, kq = (f4 & 15) * 4;
        int row = row0 + rr;
        if (row >= N_NODES) row = N_NODES - 1;
        float4 v = *(const float4*)&agg[(size_t)row * HIDDEN + kq];
        xt[kq + 0][rr] = fmaxf(v.x, 0.f); xt[kq + 1][rr] = fmaxf(v.y, 0.f);
        xt[kq + 2][rr] = fmaxf(v.z, 0.f); xt[kq + 3][rr] = fmaxf(v.w, 0.f);
    }
    __syncthreads();

    float acc[4][4];
    #pragma unroll
    for (int r = 0; r < 4; ++r)
        #pragma unroll
        for (int c = 0; c < 4; ++c) acc[r][c] = 0.0f;

    #pragma unroll 16
    for (int kk = 0; kk < 64; ++kk) {
        float4 a = *(const float4*)&xt[kk][rgrp4];
        float4 b = *(const float4*)&Ws[kk][cgrp4];
        acc[0][0] += a.x * b.x; acc[0][1] += a.x * b.y; acc[0][2] += a.x * b.z; acc[0][3] += a.x * b.w;
        acc[1][0] += a.y * b.x; acc[1][1] += a.y * b.y; acc[1][2] += a.y * b.z; acc[1][3] += a.y * b.w;
        acc[2][0] += a.z * b.x; acc[2][1] += a.z * b.y; acc[2][2] += a.z * b.z; acc[2][3] += a.z * b.w;
        acc[3][0] += a.w * b.x; acc[3][1] += a.w * b.y; acc[3][2] += a.w * b.z; acc[3][3] += a.w * b.w;
    }

    #pragma unroll
    for (int r = 0; r < 4; ++r) {
        int row = row0 + rgrp4 + r;
        if (row < N_NODES) {
            float dn = dinv[row];
            __half2* ph = (__half2*)&hws_h[(size_t)row * HIDDEN + cgrp4];
            ph[0] = __floats2half2_rn(acc[r][0] * dn, acc[r][1] * dn);
            ph[1] = __floats2half2_rn(acc[r][2] * dn, acc[r][3] * dn);
        }
    }
}

// ---------------- CSR pull: agg[d] = b + dinv[d]*(hws[d] + sum_in hws[s]) ----------------
// one wave per node, lane = channel, fp16 rows. Uniform-base addressing:
// row base from readlane result -> SALU; load = saddr + lane voffset.

__global__ __launch_bounds__(256) void pull_k(const int* __restrict__ row_ptr,
                                              const int* __restrict__ csr_src,
                                              const float* __restrict__ dinv,
                                              const __half* __restrict__ hws_h,
                                              const float* __restrict__ b,
                                              float* __restrict__ agg) {
    // wave-uniform by construction: blockIdx.x*4 + waveId
    int node = __builtin_amdgcn_readfirstlane((blockIdx.x * 256 + threadIdx.x) >> 6);
    int lane = threadIdx.x & 63;
    if (node >= N_NODES) return;   // uniform -> scalar branch

    int start = __builtin_amdgcn_readfirstlane(row_ptr[node]);
    int end   = __builtin_amdgcn_readfirstlane(row_ptr[node + 1]);

    // independent loads issued early: bias, self row (uniform base), dinv
    const __half* __restrict__ selfrow = hws_h + ((size_t)node << 6);
    float blane = b[lane];
    float a0 = __half2float(selfrow[lane]);   // self-loop term
    float dn = dinv[node];

    float a1 = 0.f, a2 = 0.f, a3 = 0.f, a4 = 0.f, a5 = 0.f, a6 = 0.f, a7 = 0.f;

    int base = start;
    while (base < end) {                       // one pass for deg<=64 (virtually always)
        int rem = end - base;                  // uniform
        int ci = base + lane;
        int lastci = end - 1;
        if (ci > lastci) ci = lastci;          // clamp into valid range (same cacheline)
        int idxv = csr_src[ci];                // ONE coalesced load: up to 64 indices
        int nch = rem < 64 ? rem : 64;

        for (int j = 0; j < nch; j += 16) {    // 16 gathers in flight per wait
            #pragma unroll
            for (int k = 0; k < 16; ++k) {
                int jj = j + k;                                    // uniform
                int s = __builtin_amdgcn_readlane(idxv, jj);       // SGPR broadcast
                const __half* __restrict__ row = hws_h + ((size_t)s << 6);  // SALU base
                float w = (jj < rem) ? 1.f : 0.f;                  // uniform pad weight
                float v = __half2float(row[lane]);                 // saddr + lane voffset
                if (k == 0)      a0 += w * v;
                else if (k == 1) a1 += w * v;
                else if (k == 2) a2 += w * v;
                else if (k == 3) a3 += w * v;
                else if (k == 4) a4 += w * v;
                else if (k == 5) a5 += w * v;
                else if (k == 6) a6 += w * v;
                else if (k == 7) a7 += w * v;
                else if (k == 8)  a0 += w * v;
                else if (k == 9)  a1 += w * v;
                else if (k == 10) a2 += w * v;
                else if (k == 11) a3 += w * v;
                else if (k == 12) a4 += w * v;
                else if (k == 13) a5 += w * v;
                else if (k == 14) a6 += w * v;
                else              a7 += w * v;
            }
        }
        base += 64;
    }

    float sum = ((a0 + a1) + (a2 + a3)) + ((a4 + a5) + (a6 + a7));
    float* __restrict__ outrow = agg + ((size_t)node << 6);   // uniform base
    outrow[lane] = blane + dn * sum;
}

// ---------------- final: out = relu(agg) @ Wl + bl ----------------

__global__ __launch_bounds__(256) void final_k(const float* __restrict__ agg,
                                               const float* __restrict__ Wl,
                                               const float* __restrict__ bl,
                                               float* __restrict__ out) {
    __shared__ float Ws[HIDDEN * N_CLASSES];
    __shared__ float hs[16][HIDDEN + 1];
    int tid = threadIdx.x;

    if (tid < HIDDEN * N_CLASSES / 4) ((float4*)Ws)[tid] = ((const float4*)Wl)[tid];

    int row0 = blockIdx.x * 16;
    for (int i = tid; i < 16 * HIDDEN; i += 256) {
        int rr = i >> 6;
        int kk = i & 63;
        hs[rr][kk] = fmaxf(agg[(size_t)(row0 + rr) * HIDDEN + kk], 0.0f);
    }
    __syncthreads();

    int col = tid & 15;
    int r = tid >> 4;
    float acc = bl[col];
    #pragma unroll
    for (int k = 0; k < HIDDEN; ++k)
        acc += hs[r][k] * Ws[k * N_CLASSES + col];
    out[(size_t)(row0 + r) * N_CLASSES + col] = acc;
}

// ---------------- launch ----------------

extern "C" void kernel_launch(void* const* d_in, const int* in_sizes, int n_in,
                              void* d_out, int out_size, void* d_ws, size_t ws_size,
                              hipStream_t stream) {
    const float* x  = (const float*)d_in[0];
    const int*   ei = (const int*)d_in[1];
    const float* W1 = (const float*)d_in[2];
    const float* b1 = (const float*)d_in[3];
    const float* W2 = (const float*)d_in[4];
    const float* b2 = (const float*)d_in[5];
    const float* Wl = (const float*)d_in[6];
    const float* bl = (const float*)d_in[7];
    float* out = (float*)d_out;

    const int* src = ei;
    const int* dst = ei + N_EDGES;

    __half* hws_h  = (__half*)d_ws;                              // N*64 halves (12.8 MB)
    float* agg     = (float*)(hws_h + (size_t)N_NODES * HIDDEN); // N*64 floats (25.6 MB)
    int2*  pairs   = (int2*)agg;                                 // aliases agg (dead before pull writes agg)
    int*   csr_src = (int*)(agg + (size_t)N_NODES * HIDDEN);     // E
    float* dinv    = (float*)(csr_src + N_EDGES);                // N
    int*   row_ptr = (int*)(dinv + N_NODES);                     // N+4
    int*   buk_cnt = row_ptr + N_NODES + 4;                      // 200
    int*   buk_off = buk_cnt + 200;                              // 200
    int*   bcur    = buk_off + 200;                              // 200

    // --- CSR build (degree counting confined to LDS) ---
    zero_buk_k<<<1, 256, 0, stream>>>(buk_cnt);
    bukhist_k<<<NHB, 256, 0, stream>>>(dst, buk_cnt);
    buk_scan_k<<<1, 256, 0, stream>>>(buk_cnt, buk_off, bcur);
    coarse_k<<<NCB, 256, 0, stream>>>(src, dst, bcur, pairs);
    fine2_k<<<NBUK, 256, 0, stream>>>(pairs, buk_off, csr_src, row_ptr, dinv);

    // --- layer 1 ---
    gemm1_tiled_k<<<GBLK, 256, 0, stream>>>(x, W1, dinv, hws_h);
    pull_k<<<(N_NODES * 64 + 255) / 256, 256, 0, stream>>>(row_ptr, csr_src, dinv,
                                                           hws_h, b1, agg);

    // --- layer 2 ---
    gemm2_tiled_k<<<GBLK, 256, 0, stream>>>(agg, W2, dinv, hws_h);
    pull_k<<<(N_NODES * 64 + 255) / 256, 256, 0, stream>>>(row_ptr, csr_src, dinv,
                                                           hws_h, b2, agg);

    // --- classifier head ---
    final_k<<<N_NODES / 16, 256, 0, stream>>>(agg, Wl, bl, out);
}

// Round 5
// 288.336 us; speedup vs baseline: 1.1195x; 1.0046x over previous
//
#include <hip/hip_runtime.h>
#include <hip/hip_fp16.h>
#include <math.h>

#define N_NODES 100000
#define N_EDGES 1600000
#define IN_FEAT 128
#define HIDDEN 64
#define N_CLASSES 16

#define TM 64
#define GBLK ((N_NODES + TM - 1) / TM)  // 1563

#define NBUK 196                        // buckets of 512 nodes (dst>>9)
#define CB 4096                         // edges per partition block
#define NCB ((N_EDGES + CB - 1) / CB)   // 391

// ---------------- deterministic two-pass bucket partition ----------------
// Replaces {zero_buk, bukhist, buk_scan, coarse}: the old coarse_k had 391
// blocks atomicAdd-rendezvousing on 196 shared counters (~28ns x chain-391
// ~ 8-11us serialized, same disease as the fixed bukhist). Now:
//   count_k:   per-block LDS hist -> plain coalesced stores to cnt[391][196]
//   colscan_k: per-bucket exclusive prefix over the 391 blocks (in-place)
//   bukoff_k:  exclusive scan of bucket totals -> buk_off
//   place_k:   recount ranks in LDS, write pairs at buk_off+colpre+rank
// No global atomics anywhere; fully deterministic slice bases.

__global__ __launch_bounds__(256) void count_k(const int* __restrict__ dst,
                                               int* __restrict__ blk_cnt) {
    __shared__ int hist[NBUK + 4];
    int tid = threadIdx.x;
    if (tid < NBUK) hist[tid] = 0;
    __syncthreads();
    int eb = blockIdx.x * CB;
    #pragma unroll
    for (int q = 0; q < 4; ++q) {
        int e4 = (eb >> 2) + tid + q * 256;
        if (e4 * 4 < N_EDGES) {   // N_EDGES % 4 == 0
            int4 d4 = ((const int4*)dst)[e4];
            atomicAdd(&hist[d4.x >> 9], 1);
            atomicAdd(&hist[d4.y >> 9], 1);
            atomicAdd(&hist[d4.z >> 9], 1);
            atomicAdd(&hist[d4.w >> 9], 1);
        }
    }
    __syncthreads();
    if (tid < NBUK) blk_cnt[blockIdx.x * NBUK + tid] = hist[tid];
}

// one block per bucket: exclusive prefix of cnt[*][b] over the 391 blocks,
// in place; column total -> coltot[b]. Loads are strided but L2-resident
// (each 64B line serves 16 buckets' blocks).
__global__ __launch_bounds__(512) void colscan_k(int* __restrict__ blk_cnt,
                                                 int* __restrict__ coltot) {
    __shared__ int sm[512];
    int b = blockIdx.x;
    int t = threadIdx.x;
    int v = (t < NCB) ? blk_cnt[t * NBUK + b] : 0;
    sm[t] = v;
    __syncthreads();
    for (int s = 1; s < 512; s <<= 1) {
        int add = (t >= s) ? sm[t - s] : 0;
        __syncthreads();
        sm[t] += add;
        __syncthreads();
    }
    if (t < NCB) blk_cnt[t * NBUK + b] = sm[t] - v;   // exclusive colpre
    if (t == NCB - 1) coltot[b] = sm[t];
}

// exclusive scan of 196 bucket totals -> buk_off (+ sentinel)
__global__ __launch_bounds__(256) void bukoff_k(const int* __restrict__ coltot,
                                                int* __restrict__ buk_off) {
    __shared__ int sm[256];
    int t = threadIdx.x;
    int v = (t < NBUK) ? coltot[t] : 0;
    sm[t] = v;
    __syncthreads();
    for (int s = 1; s < 256; s <<= 1) {
        int add = (t >= s) ? sm[t - s] : 0;
        __syncthreads();
        sm[t] += add;
        __syncthreads();
    }
    if (t < NBUK) buk_off[t] = sm[t] - v;
    if (t == 0) buk_off[NBUK] = N_EDGES;
}

// rank via LDS atomics from deterministic base; direct scatter (runs of
// ~21 contiguous pairs per (block,bucket) -> acceptable write coalescing).
__global__ __launch_bounds__(256) void place_k(const int* __restrict__ src,
                                               const int* __restrict__ dst,
                                               const int* __restrict__ colpre,
                                               const int* __restrict__ buk_off,
                                               int2* __restrict__ pairs) {
    __shared__ int cur[NBUK + 4];
    int tid = threadIdx.x;
    int blk = blockIdx.x;
    if (tid < NBUK) cur[tid] = buk_off[tid] + colpre[blk * NBUK + tid];
    __syncthreads();
    int eb = blk * CB;
    #pragma unroll
    for (int q = 0; q < 4; ++q) {
        int e4 = (eb >> 2) + tid + q * 256;
        if (e4 * 4 < N_EDGES) {
            int4 s4 = ((const int4*)src)[e4];
            int4 d4 = ((const int4*)dst)[e4];
            int r;
            r = atomicAdd(&cur[d4.x >> 9], 1); pairs[r] = make_int2(s4.x, d4.x);
            r = atomicAdd(&cur[d4.y >> 9], 1); pairs[r] = make_int2(s4.y, d4.y);
            r = atomicAdd(&cur[d4.z >> 9], 1); pairs[r] = make_int2(s4.z, d4.z);
            r = atomicAdd(&cur[d4.w >> 9], 1); pairs[r] = make_int2(s4.w, d4.w);
        }
    }
}

// ---------------- fine: per-bucket degree count (LDS) + dinv + row_ptr + placement ----------------

__global__ __launch_bounds__(256) void fine2_k(const int2* __restrict__ pairs,
                                               const int* __restrict__ buk_off,
                                               int* __restrict__ csr_src,
                                               int* __restrict__ row_ptr,
                                               float* __restrict__ dinv) {
    __shared__ int cnt[512];
    __shared__ int psc[256];
    __shared__ int cur[512];
    int b = blockIdx.x;
    int node0 = b * 512;
    int nn = N_NODES - node0;
    if (nn > 512) nn = 512;
    int tid = threadIdx.x;

    cnt[tid] = 0; cnt[tid + 256] = 0;
    __syncthreads();

    int e0 = buk_off[b];
    int e1 = buk_off[b + 1];

    for (int e = e0 + tid; e < e1; e += 256)
        atomicAdd(&cnt[pairs[e].y - node0], 1);
    __syncthreads();

    int c0 = cnt[2 * tid], c1 = cnt[2 * tid + 1];
    int p = c0 + c1;
    psc[tid] = p;
    __syncthreads();
    for (int s = 1; s < 256; s <<= 1) {
        int add = (tid >= s) ? psc[tid - s] : 0;
        __syncthreads();
        psc[tid] += add;
        __syncthreads();
    }
    int excl = psc[tid] - p;
    int g0 = e0 + excl;
    int g1 = g0 + c0;
    cur[2 * tid] = g0;
    cur[2 * tid + 1] = g1;
    if (2 * tid < nn) {
        row_ptr[node0 + 2 * tid] = g0;
        dinv[node0 + 2 * tid] = 1.0f / sqrtf((float)(c0 + 1));
    }
    if (2 * tid + 1 < nn) {
        row_ptr[node0 + 2 * tid + 1] = g1;
        dinv[node0 + 2 * tid + 1] = 1.0f / sqrtf((float)(c1 + 1));
    }
    if (b == NBUK - 1 && tid == 0) row_ptr[N_NODES] = N_EDGES;
    __syncthreads();

    for (int e = e0 + tid; e < e1; e += 256) {
        int2 pr = pairs[e];
        int pos = atomicAdd(&cur[pr.y - node0], 1);
        csr_src[pos] = pr.x;
    }
}

// ---------------- register-tiled GEMM 1: hws_h = fp16((x @ W1) * dinv[row]) ----------------

__global__ __launch_bounds__(256) void gemm1_tiled_k(const float* __restrict__ x,
                                                     const float* __restrict__ W,
                                                     const float* __restrict__ dinv,
                                                     __half* __restrict__ hws_h) {
    __shared__ float Ws[64][64];
    __shared__ float xt[64][68];
    int tid = threadIdx.x;
    int row0 = blockIdx.x * TM;
    int rgrp4 = (tid >> 4) * 4;
    int cgrp4 = (tid & 15) * 4;

    float acc[4][4];
    #pragma unroll
    for (int r = 0; r < 4; ++r)
        #pragma unroll
        for (int c = 0; c < 4; ++c) acc[r][c] = 0.0f;

    for (int k0 = 0; k0 < IN_FEAT; k0 += 64) {
        #pragma unroll
        for (int i = 0; i < 4; ++i) {
            int f4 = tid + i * 256;
            int kk = f4 >> 4, c4 = (f4 & 15) * 4;
            *(float4*)&Ws[kk][c4] = *(const float4*)&W[(size_t)(k0 + kk) * HIDDEN + c4];
        }
        #pragma unroll
        for (int i = 0; i < 4; ++i) {
            int f4 = tid + i * 256;
            int rr = f4 >> 4, kq = (f4 & 15) * 4;
            int row = row0 + rr;
            if (row >= N_NODES) row = N_NODES - 1;
            float4 v = *(const float4*)&x[(size_t)row * IN_FEAT + k0 + kq];
            xt[kq + 0][rr] = v.x; xt[kq + 1][rr] = v.y;
            xt[kq + 2][rr] = v.z; xt[kq + 3][rr] = v.w;
        }
        __syncthreads();

        #pragma unroll 16
        for (int kk = 0; kk < 64; ++kk) {
            float4 a = *(const float4*)&xt[kk][rgrp4];
            float4 b = *(const float4*)&Ws[kk][cgrp4];
            acc[0][0] += a.x * b.x; acc[0][1] += a.x * b.y; acc[0][2] += a.x * b.z; acc[0][3] += a.x * b.w;
            acc[1][0] += a.y * b.x; acc[1][1] += a.y * b.y; acc[1][2] += a.y * b.z; acc[1][3] += a.y * b.w;
            acc[2][0] += a.z * b.x; acc[2][1] += a.z * b.y; acc[2][2] += a.z * b.z; acc[2][3] += a.z * b.w;
            acc[3][0] += a.w * b.x; acc[3][1] += a.w * b.y; acc[3][2] += a.w * b.z; acc[3][3] += a.w * b.w;
        }
        __syncthreads();
    }

    #pragma unroll
    for (int r = 0; r < 4; ++r) {
        int row = row0 + rgrp4 + r;
        if (row < N_NODES) {
            float dn = dinv[row];
            __half2* ph = (__half2*)&hws_h[(size_t)row * HIDDEN + cgrp4];
            ph[0] = __floats2half2_rn(acc[r][0] * dn, acc[r][1] * dn);
            ph[1] = __floats2half2_rn(acc[r][2] * dn, acc[r][3] * dn);
        }
    }
}

// ---------------- register-tiled GEMM 2: hws_h = fp16((relu(agg) @ W2) * dinv[row]) ----------------

__global__ __launch_bounds__(256) void gemm2_tiled_k(const float* __restrict__ agg,
                                                     const float* __restrict__ W,
                                                     const float* __restrict__ dinv,
                                                     __half* __restrict__ hws_h) {
    __shared__ float Ws[64][64];
    __shared__ float xt[64][68];
    int tid = threadIdx.x;
    int row0 = blockIdx.x * TM;
    int rgrp4 = (tid >> 4) * 4;
    int cgrp4 = (tid & 15) * 4;

    #pragma unroll
    for (int i = 0; i < 4; ++i) {
        int f4 = tid + i * 256;
        int kk = f4 >> 4, c4 = (f4 & 15) * 4;
        *(float4*)&Ws[kk][c4] = *(const float4*)&W[(size_t)kk * HIDDEN + c4];
    }
    #pragma unroll
    for (int i = 0; i < 4; ++i) {
        int f4 = tid + i * 256;
        int rr = f4 >> 4, kq = (f4 & 15) * 4;
        int row = row0 + rr;
        if (row >= N_NODES) row = N_NODES - 1;
        float4 v = *(const float4*)&agg[(size_t)row * HIDDEN + kq];
        xt[kq + 0][rr] = fmaxf(v.x, 0.f); xt[kq + 1][rr] = fmaxf(v.y, 0.f);
        xt[kq + 2][rr] = fmaxf(v.z, 0.f); xt[kq + 3][rr] = fmaxf(v.w, 0.f);
    }
    __syncthreads();

    float acc[4][4];
    #pragma unroll
    for (int r = 0; r < 4; ++r)
        #pragma unroll
        for (int c = 0; c < 4; ++c) acc[r][c] = 0.0f;

    #pragma unroll 16
    for (int kk = 0; kk < 64; ++kk) {
        float4 a = *(const float4*)&xt[kk][rgrp4];
        float4 b = *(const float4*)&Ws[kk][cgrp4];
        acc[0][0] += a.x * b.x; acc[0][1] += a.x * b.y; acc[0][2] += a.x * b.z; acc[0][3] += a.x * b.w;
        acc[1][0] += a.y * b.x; acc[1][1] += a.y * b.y; acc[1][2] += a.y * b.z; acc[1][3] += a.y * b.w;
        acc[2][0] += a.z * b.x; acc[2][1] += a.z * b.y; acc[2][2] += a.z * b.z; acc[2][3] += a.z * b.w;
        acc[3][0] += a.w * b.x; acc[3][1] += a.w * b.y; acc[3][2] += a.w * b.z; acc[3][3] += a.w * b.w;
    }

    #pragma unroll
    for (int r = 0; r < 4; ++r) {
        int row = row0 + rgrp4 + r;
        if (row < N_NODES) {
            float dn = dinv[row];
            __half2* ph = (__half2*)&hws_h[(size_t)row * HIDDEN + cgrp4];
            ph[0] = __floats2half2_rn(acc[r][0] * dn, acc[r][1] * dn);
            ph[1] = __floats2half2_rn(acc[r][2] * dn, acc[r][3] * dn);
        }
    }
}

// ---------------- CSR pull: agg[d] = b + dinv[d]*(hws[d] + sum_in hws[s]) ----------------
// one wave per node, lane = channel, fp16 rows, uniform-base gathers.
//
// KEY CHANGE (this round): 32 gathers in flight before any consume (was 16).
// pull is latency/MLP-bound (VALU cuts were ~neutral; chain cuts helped), so
// for deg<=32 (~all Poisson-16 nodes) the chain is now:
//   row_ptr -> idx_vec -> ONE 32-wide gather window   (3 serial latencies)
// and the in-flight line count per wave in the gather phase doubles.

#define GATH(K, ACC)                                                        \
    { int s_ = __builtin_amdgcn_readlane(idxv, (C) + (K));                  \
      const __half* row_ = hws_h + ((size_t)s_ << 6);                       \
      float w_ = ((K) < rem) ? 1.f : 0.f;                                   \
      ACC += w_ * __half2float(row_[lane]); }

#define GATH8(B)                                                            \
    GATH((B) + 0, a0) GATH((B) + 1, a1) GATH((B) + 2, a2) GATH((B) + 3, a3) \
    GATH((B) + 4, a4) GATH((B) + 5, a5) GATH((B) + 6, a6) GATH((B) + 7, a7)

__global__ __launch_bounds__(256) void pull_k(const int* __restrict__ row_ptr,
                                              const int* __restrict__ csr_src,
                                              const float* __restrict__ dinv,
                                              const __half* __restrict__ hws_h,
                                              const float* __restrict__ b,
                                              float* __restrict__ agg) {
    // wave-uniform by construction: blockIdx.x*4 + waveId
    int node = __builtin_amdgcn_readfirstlane((blockIdx.x * 256 + threadIdx.x) >> 6);
    int lane = threadIdx.x & 63;
    if (node >= N_NODES) return;   // uniform -> scalar branch

    int start = __builtin_amdgcn_readfirstlane(row_ptr[node]);
    int end   = __builtin_amdgcn_readfirstlane(row_ptr[node + 1]);

    const __half* __restrict__ selfrow = hws_h + ((size_t)node << 6);
    float blane = b[lane];
    float a0 = __half2float(selfrow[lane]);   // self-loop term
    float dn = dinv[node];

    float a1 = 0.f, a2 = 0.f, a3 = 0.f, a4 = 0.f, a5 = 0.f, a6 = 0.f, a7 = 0.f;

    int base = start;
    while (base < end) {                    // one pass for deg<=64 (virtually always)
        int ci = base + lane;
        int last = end - 1;
        if (ci > last) ci = last;           // clamp (same cacheline region)
        int idxv = csr_src[ci];             // ONE coalesced load: up to 64 indices

        int rem = end - base;               // uniform; >=1
        {   // chunk 0: 32 gathers, single wait window
            const int C = 0;
            GATH8(0) GATH8(8) GATH8(16) GATH8(24)
        }
        if (base + 32 < end) {              // chunk 1 (deg 33..64 in this window)
            const int C = 32;
            rem = end - base - 32;          // uniform, in [1,32]
            GATH8(0) GATH8(8) GATH8(16) GATH8(24)
        }
        base += 64;
    }

    float sum = ((a0 + a1) + (a2 + a3)) + ((a4 + a5) + (a6 + a7));
    float* __restrict__ outrow = agg + ((size_t)node << 6);   // uniform base
    outrow[lane] = blane + dn * sum;
}

// ---------------- final: out = relu(agg) @ Wl + bl ----------------

__global__ __launch_bounds__(256) void final_k(const float* __restrict__ agg,
                                               const float* __restrict__ Wl,
                                               const float* __restrict__ bl,
                                               float* __restrict__ out) {
    __shared__ float Ws[HIDDEN * N_CLASSES];
    __shared__ float hs[16][HIDDEN + 1];
    int tid = threadIdx.x;

    if (tid < HIDDEN * N_CLASSES / 4) ((float4*)Ws)[tid] = ((const float4*)Wl)[tid];

    int row0 = blockIdx.x * 16;
    for (int i = tid; i < 16 * HIDDEN; i += 256) {
        int rr = i >> 6;
        int kk = i & 63;
        hs[rr][kk] = fmaxf(agg[(size_t)(row0 + rr) * HIDDEN + kk], 0.0f);
    }
    __syncthreads();

    int col = tid & 15;
    int r = tid >> 4;
    float acc = bl[col];
    #pragma unroll
    for (int k = 0; k < HIDDEN; ++k)
        acc += hs[r][k] * Ws[k * N_CLASSES + col];
    out[(size_t)(row0 + r) * N_CLASSES + col] = acc;
}

// ---------------- launch ----------------

extern "C" void kernel_launch(void* const* d_in, const int* in_sizes, int n_in,
                              void* d_out, int out_size, void* d_ws, size_t ws_size,
                              hipStream_t stream) {
    const float* x  = (const float*)d_in[0];
    const int*   ei = (const int*)d_in[1];
    const float* W1 = (const float*)d_in[2];
    const float* b1 = (const float*)d_in[3];
    const float* W2 = (const float*)d_in[4];
    const float* b2 = (const float*)d_in[5];
    const float* Wl = (const float*)d_in[6];
    const float* bl = (const float*)d_in[7];
    float* out = (float*)d_out;

    const int* src = ei;
    const int* dst = ei + N_EDGES;

    __half* hws_h  = (__half*)d_ws;                              // N*64 halves (12.8 MB)
    float* agg     = (float*)(hws_h + (size_t)N_NODES * HIDDEN); // N*64 floats (25.6 MB)
    int2*  pairs   = (int2*)agg;                                 // aliases agg (dead before pull writes agg)
    int*   csr_src = (int*)(agg + (size_t)N_NODES * HIDDEN);     // E
    float* dinv    = (float*)(csr_src + N_EDGES);                // N
    int*   row_ptr = (int*)(dinv + N_NODES);                     // N+4
    int*   buk_cnt = row_ptr + N_NODES + 4;                      // 200 (unused legacy slot)
    int*   buk_off = buk_cnt + 200;                              // 200
    int*   coltot  = buk_off + 200;                              // 200
    // 391x196 count/colpre matrix aliases csr_src (csr_src written later by fine2)
    int*   blk_cnt = csr_src;

    // --- CSR build (deterministic, atomic-free partition) ---
    count_k<<<NCB, 256, 0, stream>>>(dst, blk_cnt);
    colscan_k<<<NBUK, 512, 0, stream>>>(blk_cnt, coltot);
    bukoff_k<<<1, 256, 0, stream>>>(coltot, buk_off);
    place_k<<<NCB, 256, 0, stream>>>(src, dst, blk_cnt, buk_off, pairs);
    fine2_k<<<NBUK, 256, 0, stream>>>(pairs, buk_off, csr_src, row_ptr, dinv);

    // --- layer 1 ---
    gemm1_tiled_k<<<GBLK, 256, 0, stream>>>(x, W1, dinv, hws_h);
    pull_k<<<(N_NODES * 64 + 255) / 256, 256, 0, stream>>>(row_ptr, csr_src, dinv,
                                                           hws_h, b1, agg);

    // --- layer 2 ---
    gemm2_tiled_k<<<GBLK, 256, 0, stream>>>(agg, W2, dinv, hws_h);
    pull_k<<<(N_NODES * 64 + 255) / 256, 256, 0, stream>>>(row_ptr, csr_src, dinv,
                                                           hws_h, b2, agg);

    // --- classifier head ---
    final_k<<<N_NODES / 16, 256, 0, stream>>>(agg, Wl, bl, out);
}

// Round 6
// 280.388 us; speedup vs baseline: 1.1512x; 1.0283x over previous
//
#include <hip/hip_runtime.h>
#include <hip/hip_fp16.h>
#include <math.h>

#define N_NODES 100000
#define N_EDGES 1600000
#define IN_FEAT 128
#define HIDDEN 64
#define N_CLASSES 16

#define TM 64
#define GBLK ((N_NODES + TM - 1) / TM)  // 1563

#define NBUK 196                        // buckets of 512 nodes (dst>>9)
#define CB 4096                         // edges per partition block
#define NCB ((N_EDGES + CB - 1) / CB)   // 391

// ---------------- deterministic two-pass bucket partition ----------------
// count_k:   per-block LDS hist -> plain coalesced stores to cnt[391][196]
// colscan_k: per-bucket exclusive prefix over the 391 blocks (in-place)
// bukoff_k:  exclusive scan of bucket totals -> buk_off
// place_k:   recount ranks in LDS, write pairs at buk_off+colpre+rank
// No global atomics anywhere (same-address atomic rendezvous costs
// ~28ns x chain-length; this was 44us in bukhist and ~10us in coarse).

__global__ __launch_bounds__(256) void count_k(const int* __restrict__ dst,
                                               int* __restrict__ blk_cnt) {
    __shared__ int hist[NBUK + 4];
    int tid = threadIdx.x;
    if (tid < NBUK) hist[tid] = 0;
    __syncthreads();
    int eb = blockIdx.x * CB;
    #pragma unroll
    for (int q = 0; q < 4; ++q) {
        int e4 = (eb >> 2) + tid + q * 256;
        if (e4 * 4 < N_EDGES) {   // N_EDGES % 4 == 0
            int4 d4 = ((const int4*)dst)[e4];
            atomicAdd(&hist[d4.x >> 9], 1);
            atomicAdd(&hist[d4.y >> 9], 1);
            atomicAdd(&hist[d4.z >> 9], 1);
            atomicAdd(&hist[d4.w >> 9], 1);
        }
    }
    __syncthreads();
    if (tid < NBUK) blk_cnt[blockIdx.x * NBUK + tid] = hist[tid];
}

// one block per bucket: exclusive prefix of cnt[*][b] over the 391 blocks,
// in place; column total -> coltot[b].
__global__ __launch_bounds__(512) void colscan_k(int* __restrict__ blk_cnt,
                                                 int* __restrict__ coltot) {
    __shared__ int sm[512];
    int b = blockIdx.x;
    int t = threadIdx.x;
    int v = (t < NCB) ? blk_cnt[t * NBUK + b] : 0;
    sm[t] = v;
    __syncthreads();
    for (int s = 1; s < 512; s <<= 1) {
        int add = (t >= s) ? sm[t - s] : 0;
        __syncthreads();
        sm[t] += add;
        __syncthreads();
    }
    if (t < NCB) blk_cnt[t * NBUK + b] = sm[t] - v;   // exclusive colpre
    if (t == NCB - 1) coltot[b] = sm[t];
}

// exclusive scan of 196 bucket totals -> buk_off (+ sentinel)
__global__ __launch_bounds__(256) void bukoff_k(const int* __restrict__ coltot,
                                                int* __restrict__ buk_off) {
    __shared__ int sm[256];
    int t = threadIdx.x;
    int v = (t < NBUK) ? coltot[t] : 0;
    sm[t] = v;
    __syncthreads();
    for (int s = 1; s < 256; s <<= 1) {
        int add = (t >= s) ? sm[t - s] : 0;
        __syncthreads();
        sm[t] += add;
        __syncthreads();
    }
    if (t < NBUK) buk_off[t] = sm[t] - v;
    if (t == 0) buk_off[NBUK] = N_EDGES;
}

// rank via LDS atomics from deterministic base; direct scatter.
__global__ __launch_bounds__(256) void place_k(const int* __restrict__ src,
                                               const int* __restrict__ dst,
                                               const int* __restrict__ colpre,
                                               const int* __restrict__ buk_off,
                                               int2* __restrict__ pairs) {
    __shared__ int cur[NBUK + 4];
    int tid = threadIdx.x;
    int blk = blockIdx.x;
    if (tid < NBUK) cur[tid] = buk_off[tid] + colpre[blk * NBUK + tid];
    __syncthreads();
    int eb = blk * CB;
    #pragma unroll
    for (int q = 0; q < 4; ++q) {
        int e4 = (eb >> 2) + tid + q * 256;
        if (e4 * 4 < N_EDGES) {
            int4 s4 = ((const int4*)src)[e4];
            int4 d4 = ((const int4*)dst)[e4];
            int r;
            r = atomicAdd(&cur[d4.x >> 9], 1); pairs[r] = make_int2(s4.x, d4.x);
            r = atomicAdd(&cur[d4.y >> 9], 1); pairs[r] = make_int2(s4.y, d4.y);
            r = atomicAdd(&cur[d4.z >> 9], 1); pairs[r] = make_int2(s4.z, d4.z);
            r = atomicAdd(&cur[d4.w >> 9], 1); pairs[r] = make_int2(s4.w, d4.w);
        }
    }
}

// ---------------- fine: per-bucket degree count (LDS) + dinv + row_ptr + placement ----------------

__global__ __launch_bounds__(256) void fine2_k(const int2* __restrict__ pairs,
                                               const int* __restrict__ buk_off,
                                               int* __restrict__ csr_src,
                                               int* __restrict__ row_ptr,
                                               float* __restrict__ dinv) {
    __shared__ int cnt[512];
    __shared__ int psc[256];
    __shared__ int cur[512];
    int b = blockIdx.x;
    int node0 = b * 512;
    int nn = N_NODES - node0;
    if (nn > 512) nn = 512;
    int tid = threadIdx.x;

    cnt[tid] = 0; cnt[tid + 256] = 0;
    __syncthreads();

    int e0 = buk_off[b];
    int e1 = buk_off[b + 1];

    for (int e = e0 + tid; e < e1; e += 256)
        atomicAdd(&cnt[pairs[e].y - node0], 1);
    __syncthreads();

    int c0 = cnt[2 * tid], c1 = cnt[2 * tid + 1];
    int p = c0 + c1;
    psc[tid] = p;
    __syncthreads();
    for (int s = 1; s < 256; s <<= 1) {
        int add = (tid >= s) ? psc[tid - s] : 0;
        __syncthreads();
        psc[tid] += add;
        __syncthreads();
    }
    int excl = psc[tid] - p;
    int g0 = e0 + excl;
    int g1 = g0 + c0;
    cur[2 * tid] = g0;
    cur[2 * tid + 1] = g1;
    if (2 * tid < nn) {
        row_ptr[node0 + 2 * tid] = g0;
        dinv[node0 + 2 * tid] = 1.0f / sqrtf((float)(c0 + 1));
    }
    if (2 * tid + 1 < nn) {
        row_ptr[node0 + 2 * tid + 1] = g1;
        dinv[node0 + 2 * tid + 1] = 1.0f / sqrtf((float)(c1 + 1));
    }
    if (b == NBUK - 1 && tid == 0) row_ptr[N_NODES] = N_EDGES;
    __syncthreads();

    for (int e = e0 + tid; e < e1; e += 256) {
        int2 pr = pairs[e];
        int pos = atomicAdd(&cur[pr.y - node0], 1);
        csr_src[pos] = pr.x;
    }
}

// ---------------- register-tiled GEMM 1: hws_h = fp16((x @ W1) * dinv[row]) ----------------

__global__ __launch_bounds__(256) void gemm1_tiled_k(const float* __restrict__ x,
                                                     const float* __restrict__ W,
                                                     const float* __restrict__ dinv,
                                                     __half* __restrict__ hws_h) {
    __shared__ float Ws[64][64];
    __shared__ float xt[64][68];
    int tid = threadIdx.x;
    int row0 = blockIdx.x * TM;
    int rgrp4 = (tid >> 4) * 4;
    int cgrp4 = (tid & 15) * 4;

    float acc[4][4];
    #pragma unroll
    for (int r = 0; r < 4; ++r)
        #pragma unroll
        for (int c = 0; c < 4; ++c) acc[r][c] = 0.0f;

    for (int k0 = 0; k0 < IN_FEAT; k0 += 64) {
        #pragma unroll
        for (int i = 0; i < 4; ++i) {
            int f4 = tid + i * 256;
            int kk = f4 >> 4, c4 = (f4 & 15) * 4;
            *(float4*)&Ws[kk][c4] = *(const float4*)&W[(size_t)(k0 + kk) * HIDDEN + c4];
        }
        #pragma unroll
        for (int i = 0; i < 4; ++i) {
            int f4 = tid + i * 256;
            int rr = f4 >> 4, kq = (f4 & 15) * 4;
            int row = row0 + rr;
            if (row >= N_NODES) row = N_NODES - 1;
            float4 v = *(const float4*)&x[(size_t)row * IN_FEAT + k0 + kq];
            xt[kq + 0][rr] = v.x; xt[kq + 1][rr] = v.y;
            xt[kq + 2][rr] = v.z; xt[kq + 3][rr] = v.w;
        }
        __syncthreads();

        #pragma unroll 16
        for (int kk = 0; kk < 64; ++kk) {
            float4 a = *(const float4*)&xt[kk][rgrp4];
            float4 b = *(const float4*)&Ws[kk][cgrp4];
            acc[0][0] += a.x * b.x; acc[0][1] += a.x * b.y; acc[0][2] += a.x * b.z; acc[0][3] += a.x * b.w;
            acc[1][0] += a.y * b.x; acc[1][1] += a.y * b.y; acc[1][2] += a.y * b.z; acc[1][3] += a.y * b.w;
            acc[2][0] += a.z * b.x; acc[2][1] += a.z * b.y; acc[2][2] += a.z * b.z; acc[2][3] += a.z * b.w;
            acc[3][0] += a.w * b.x; acc[3][1] += a.w * b.y; acc[3][2] += a.w * b.z; acc[3][3] += a.w * b.w;
        }
        __syncthreads();
    }

    #pragma unroll
    for (int r = 0; r < 4; ++r) {
        int row = row0 + rgrp4 + r;
        if (row < N_NODES) {
            float dn = dinv[row];
            __half2* ph = (__half2*)&hws_h[(size_t)row * HIDDEN + cgrp4];
            ph[0] = __floats2half2_rn(acc[r][0] * dn, acc[r][1] * dn);
            ph[1] = __floats2half2_rn(acc[r][2] * dn, acc[r][3] * dn);
        }
    }
}

// ---------------- register-tiled GEMM 2: hws_h = fp16((relu(agg) @ W2) * dinv[row]) ----------------

__global__ __launch_bounds__(256) void gemm2_tiled_k(const float* __restrict__ agg,
                                                     const float* __restrict__ W,
                                                     const float* __restrict__ dinv,
                                                     __half* __restrict__ hws_h) {
    __shared__ float Ws[64][64];
    __shared__ float xt[64][68];
    int tid = threadIdx.x;
    int row0 = blockIdx.x * TM;
    int rgrp4 = (tid >> 4) * 4;
    int cgrp4 = (tid & 15) * 4;

    #pragma unroll
    for (int i = 0; i < 4; ++i) {
        int f4 = tid + i * 256;
        int kk = f4 >> 4, c4 = (f4 & 15) * 4;
        *(float4*)&Ws[kk][c4] = *(const float4*)&W[(size_t)kk * HIDDEN + c4];
    }
    #pragma unroll
    for (int i = 0; i < 4; ++i) {
        int f4 = tid + i * 256;
        int rr = f4 >> 4, kq = (f4 & 15) * 4;
        int row = row0 + rr;
        if (row >= N_NODES) row = N_NODES - 1;
        float4 v = *(const float4*)&agg[(size_t)row * HIDDEN + kq];
        xt[kq + 0][rr] = fmaxf(v.x, 0.f); xt[kq + 1][rr] = fmaxf(v.y, 0.f);
        xt[kq + 2][rr] = fmaxf(v.z, 0.f); xt[kq + 3][rr] = fmaxf(v.w, 0.f);
    }
    __syncthreads();

    float acc[4][4];
    #pragma unroll
    for (int r = 0; r < 4; ++r)
        #pragma unroll
        for (int c = 0; c < 4; ++c) acc[r][c] = 0.0f;

    #pragma unroll 16
    for (int kk = 0; kk < 64; ++kk) {
        float4 a = *(const float4*)&xt[kk][rgrp4];
        float4 b = *(const float4*)&Ws[kk][cgrp4];
        acc[0][0] += a.x * b.x; acc[0][1] += a.x * b.y; acc[0][2] += a.x * b.z; acc[0][3] += a.x * b.w;
        acc[1][0] += a.y * b.x; acc[1][1] += a.y * b.y; acc[1][2] += a.y * b.z; acc[1][3] += a.y * b.w;
        acc[2][0] += a.z * b.x; acc[2][1] += a.z * b.y; acc[2][2] += a.z * b.z; acc[2][3] += a.z * b.w;
        acc[3][0] += a.w * b.x; acc[3][1] += a.w * b.y; acc[3][2] += a.w * b.z; acc[3][3] += a.w * b.w;
    }

    #pragma unroll
    for (int r = 0; r < 4; ++r) {
        int row = row0 + rgrp4 + r;
        if (row < N_NODES) {
            float dn = dinv[row];
            __half2* ph = (__half2*)&hws_h[(size_t)row * HIDDEN + cgrp4];
            ph[0] = __floats2half2_rn(acc[r][0] * dn, acc[r][1] * dn);
            ph[1] = __floats2half2_rn(acc[r][2] * dn, acc[r][3] * dn);
        }
    }
}

// ---------------- CSR pull: agg[d] = b + dinv[d]*(hws[d] + sum_in hws[s]) ----------------
// one wave per node, lane = channel, fp16 rows, uniform-base gathers.
// REVERTED to the 16-wide gather window (round-3 config, 42.3us): the 32-wide
// window A/B-regressed to 47.6us -> pull is at a gather SERVICE-RATE wall
// (L2-miss traffic ~= 8 XCDs x 12.8MB table = compulsory), not latency-bound;
// wider windows only add queueing + VGPR pressure.

__global__ __launch_bounds__(256) void pull_k(const int* __restrict__ row_ptr,
                                              const int* __restrict__ csr_src,
                                              const float* __restrict__ dinv,
                                              const __half* __restrict__ hws_h,
                                              const float* __restrict__ b,
                                              float* __restrict__ agg) {
    // wave-uniform by construction: blockIdx.x*4 + waveId
    int node = __builtin_amdgcn_readfirstlane((blockIdx.x * 256 + threadIdx.x) >> 6);
    int lane = threadIdx.x & 63;
    if (node >= N_NODES) return;   // uniform -> scalar branch

    int start = __builtin_amdgcn_readfirstlane(row_ptr[node]);
    int end   = __builtin_amdgcn_readfirstlane(row_ptr[node + 1]);

    // independent loads issued early: bias, self row (uniform base), dinv
    const __half* __restrict__ selfrow = hws_h + ((size_t)node << 6);
    float blane = b[lane];
    float a0 = __half2float(selfrow[lane]);   // self-loop term
    float dn = dinv[node];

    float a1 = 0.f, a2 = 0.f, a3 = 0.f, a4 = 0.f, a5 = 0.f, a6 = 0.f, a7 = 0.f;

    int base = start;
    while (base < end) {                       // one pass for deg<=64 (virtually always)
        int rem = end - base;                  // uniform
        int ci = base + lane;
        int lastci = end - 1;
        if (ci > lastci) ci = lastci;          // clamp into valid range (same cacheline)
        int idxv = csr_src[ci];                // ONE coalesced load: up to 64 indices
        int nch = rem < 64 ? rem : 64;

        for (int j = 0; j < nch; j += 16) {    // 16 gathers in flight per wait
            #pragma unroll
            for (int k = 0; k < 16; ++k) {
                int jj = j + k;                                    // uniform
                int s = __builtin_amdgcn_readlane(idxv, jj);       // SGPR broadcast
                const __half* __restrict__ row = hws_h + ((size_t)s << 6);  // SALU base
                float w = (jj < rem) ? 1.f : 0.f;                  // uniform pad weight
                float v = __half2float(row[lane]);                 // saddr + lane voffset
                if (k == 0)      a0 += w * v;
                else if (k == 1) a1 += w * v;
                else if (k == 2) a2 += w * v;
                else if (k == 3) a3 += w * v;
                else if (k == 4) a4 += w * v;
                else if (k == 5) a5 += w * v;
                else if (k == 6) a6 += w * v;
                else if (k == 7) a7 += w * v;
                else if (k == 8)  a0 += w * v;
                else if (k == 9)  a1 += w * v;
                else if (k == 10) a2 += w * v;
                else if (k == 11) a3 += w * v;
                else if (k == 12) a4 += w * v;
                else if (k == 13) a5 += w * v;
                else if (k == 14) a6 += w * v;
                else              a7 += w * v;
            }
        }
        base += 64;
    }

    float sum = ((a0 + a1) + (a2 + a3)) + ((a4 + a5) + (a6 + a7));
    float* __restrict__ outrow = agg + ((size_t)node << 6);   // uniform base
    outrow[lane] = blane + dn * sum;
}

// ---------------- final: out = relu(agg) @ Wl + bl ----------------

__global__ __launch_bounds__(256) void final_k(const float* __restrict__ agg,
                                               const float* __restrict__ Wl,
                                               const float* __restrict__ bl,
                                               float* __restrict__ out) {
    __shared__ float Ws[HIDDEN * N_CLASSES];
    __shared__ float hs[16][HIDDEN + 1];
    int tid = threadIdx.x;

    if (tid < HIDDEN * N_CLASSES / 4) ((float4*)Ws)[tid] = ((const float4*)Wl)[tid];

    int row0 = blockIdx.x * 16;
    for (int i = tid; i < 16 * HIDDEN; i += 256) {
        int rr = i >> 6;
        int kk = i & 63;
        hs[rr][kk] = fmaxf(agg[(size_t)(row0 + rr) * HIDDEN + kk], 0.0f);
    }
    __syncthreads();

    int col = tid & 15;
    int r = tid >> 4;
    float acc = bl[col];
    #pragma unroll
    for (int k = 0; k < HIDDEN; ++k)
        acc += hs[r][k] * Ws[k * N_CLASSES + col];
    out[(size_t)(row0 + r) * N_CLASSES + col] = acc;
}

// ---------------- launch ----------------

extern "C" void kernel_launch(void* const* d_in, const int* in_sizes, int n_in,
                              void* d_out, int out_size, void* d_ws, size_t ws_size,
                              hipStream_t stream) {
    const float* x  = (const float*)d_in[0];
    const int*   ei = (const int*)d_in[1];
    const float* W1 = (const float*)d_in[2];
    const float* b1 = (const float*)d_in[3];
    const float* W2 = (const float*)d_in[4];
    const float* b2 = (const float*)d_in[5];
    const float* Wl = (const float*)d_in[6];
    const float* bl = (const float*)d_in[7];
    float* out = (float*)d_out;

    const int* src = ei;
    const int* dst = ei + N_EDGES;

    __half* hws_h  = (__half*)d_ws;                              // N*64 halves (12.8 MB)
    float* agg     = (float*)(hws_h + (size_t)N_NODES * HIDDEN); // N*64 floats (25.6 MB)
    int2*  pairs   = (int2*)agg;                                 // aliases agg (dead before pull writes agg)
    int*   csr_src = (int*)(agg + (size_t)N_NODES * HIDDEN);     // E
    float* dinv    = (float*)(csr_src + N_EDGES);                // N
    int*   row_ptr = (int*)(dinv + N_NODES);                     // N+4
    int*   buk_cnt = row_ptr + N_NODES + 4;                      // 200 (unused legacy slot)
    int*   buk_off = buk_cnt + 200;                              // 200
    int*   coltot  = buk_off + 200;                              // 200
    // 391x196 count/colpre matrix aliases csr_src (csr_src written later by fine2)
    int*   blk_cnt = csr_src;

    // --- CSR build (deterministic, atomic-free partition) ---
    count_k<<<NCB, 256, 0, stream>>>(dst, blk_cnt);
    colscan_k<<<NBUK, 512, 0, stream>>>(blk_cnt, coltot);
    bukoff_k<<<1, 256, 0, stream>>>(coltot, buk_off);
    place_k<<<NCB, 256, 0, stream>>>(src, dst, blk_cnt, buk_off, pairs);
    fine2_k<<<NBUK, 256, 0, stream>>>(pairs, buk_off, csr_src, row_ptr, dinv);

    // --- layer 1 ---
    gemm1_tiled_k<<<GBLK, 256, 0, stream>>>(x, W1, dinv, hws_h);
    pull_k<<<(N_NODES * 64 + 255) / 256, 256, 0, stream>>>(row_ptr, csr_src, dinv,
                                                           hws_h, b1, agg);

    // --- layer 2 ---
    gemm2_tiled_k<<<GBLK, 256, 0, stream>>>(agg, W2, dinv, hws_h);
    pull_k<<<(N_NODES * 64 + 255) / 256, 256, 0, stream>>>(row_ptr, csr_src, dinv,
                                                           hws_h, b2, agg);

    // --- classifier head ---
    final_k<<<N_NODES / 16, 256, 0, stream>>>(agg, Wl, bl, out);
}

// Round 7
// 265.515 us; speedup vs baseline: 1.2157x; 1.0560x over previous
//
#include <hip/hip_runtime.h>
#include <hip/hip_fp16.h>
#include <math.h>

#define N_NODES 100000
#define N_EDGES 1600000
#define IN_FEAT 128
#define HIDDEN 64
#define N_CLASSES 16

#define TM 64
#define GBLK ((N_NODES + TM - 1) / TM)  // 1563

#define NBUK 196                        // buckets of 512 nodes (dst>>9)
#define CB 4096                         // edges per partition block
#define NCB ((N_EDGES + CB - 1) / CB)   // 391

// pack: src in bits 0..16 (src<2^17), local dst (dst&511) in bits 17..25
#define PACK(s, d)  ((s) | (((d) & 511) << 17))
#define P_SRC(p)    ((p) & 0x1FFFF)
#define P_LOC(p)    (((unsigned)(p)) >> 17)

// ---------------- deterministic two-pass bucket partition ----------------
// No global atomics anywhere (same-address atomic rendezvous costs
// ~28ns x chain-length; was 44us in bukhist, ~10us in coarse).

__global__ __launch_bounds__(256) void count_k(const int* __restrict__ dst,
                                               int* __restrict__ blk_cnt) {
    __shared__ int hist[NBUK + 4];
    int tid = threadIdx.x;
    if (tid < NBUK) hist[tid] = 0;
    __syncthreads();
    int eb = blockIdx.x * CB;
    #pragma unroll
    for (int q = 0; q < 4; ++q) {
        int e4 = (eb >> 2) + tid + q * 256;
        if (e4 * 4 < N_EDGES) {   // N_EDGES % 4 == 0
            int4 d4 = ((const int4*)dst)[e4];
            atomicAdd(&hist[d4.x >> 9], 1);
            atomicAdd(&hist[d4.y >> 9], 1);
            atomicAdd(&hist[d4.z >> 9], 1);
            atomicAdd(&hist[d4.w >> 9], 1);
        }
    }
    __syncthreads();
    if (tid < NBUK) blk_cnt[blockIdx.x * NBUK + tid] = hist[tid];
}

// one block per bucket: exclusive prefix of cnt[*][b] over the 391 blocks,
// in place; column total -> coltot[b].
__global__ __launch_bounds__(512) void colscan_k(int* __restrict__ blk_cnt,
                                                 int* __restrict__ coltot) {
    __shared__ int sm[512];
    int b = blockIdx.x;
    int t = threadIdx.x;
    int v = (t < NCB) ? blk_cnt[t * NBUK + b] : 0;
    sm[t] = v;
    __syncthreads();
    for (int s = 1; s < 512; s <<= 1) {
        int add = (t >= s) ? sm[t - s] : 0;
        __syncthreads();
        sm[t] += add;
        __syncthreads();
    }
    if (t < NCB) blk_cnt[t * NBUK + b] = sm[t] - v;   // exclusive colpre
    if (t == NCB - 1) coltot[b] = sm[t];
}

// exclusive scan of 196 bucket totals -> buk_off (+ sentinel)
__global__ __launch_bounds__(256) void bukoff_k(const int* __restrict__ coltot,
                                                int* __restrict__ buk_off) {
    __shared__ int sm[256];
    int t = threadIdx.x;
    int v = (t < NBUK) ? coltot[t] : 0;
    sm[t] = v;
    __syncthreads();
    for (int s = 1; s < 256; s <<= 1) {
        int add = (t >= s) ? sm[t - s] : 0;
        __syncthreads();
        sm[t] += add;
        __syncthreads();
    }
    if (t < NBUK) buk_off[t] = sm[t] - v;
    if (t == 0) buk_off[NBUK] = N_EDGES;
}

// rank via LDS atomics from deterministic base; direct scatter of PACKED
// edges (4 B/edge, was int2 8 B -> halved scatter write).
__global__ __launch_bounds__(256) void place_k(const int* __restrict__ src,
                                               const int* __restrict__ dst,
                                               const int* __restrict__ colpre,
                                               const int* __restrict__ buk_off,
                                               int* __restrict__ pairs_p) {
    __shared__ int cur[NBUK + 4];
    int tid = threadIdx.x;
    int blk = blockIdx.x;
    if (tid < NBUK) cur[tid] = buk_off[tid] + colpre[blk * NBUK + tid];
    __syncthreads();
    int eb = blk * CB;
    #pragma unroll
    for (int q = 0; q < 4; ++q) {
        int e4 = (eb >> 2) + tid + q * 256;
        if (e4 * 4 < N_EDGES) {
            int4 s4 = ((const int4*)src)[e4];
            int4 d4 = ((const int4*)dst)[e4];
            int r;
            r = atomicAdd(&cur[d4.x >> 9], 1); pairs_p[r] = PACK(s4.x, d4.x);
            r = atomicAdd(&cur[d4.y >> 9], 1); pairs_p[r] = PACK(s4.y, d4.y);
            r = atomicAdd(&cur[d4.z >> 9], 1); pairs_p[r] = PACK(s4.z, d4.z);
            r = atomicAdd(&cur[d4.w >> 9], 1); pairs_p[r] = PACK(s4.w, d4.w);
        }
    }
}

// ---------------- fine: SINGLE-PASS per-bucket CSR build ----------------
// Stage the bucket's packed edges in LDS (mean 8163, cap 12288 = 48 KB;
// global-2-pass fallback for oversize buckets), count+scan+place from LDS.
// Removes the second global pass over pairs (was 12.8 MB re-read).

#define FCAP 12288

__global__ __launch_bounds__(256) void fine2_k(const int* __restrict__ pairs_p,
                                               const int* __restrict__ buk_off,
                                               int* __restrict__ csr_src,
                                               int* __restrict__ row_ptr,
                                               float* __restrict__ dinv) {
    __shared__ int stage[FCAP];
    __shared__ int cnt[512];
    __shared__ int psc[256];
    __shared__ int cur[512];
    int b = blockIdx.x;
    int node0 = b * 512;
    int nn = N_NODES - node0;
    if (nn > 512) nn = 512;
    int tid = threadIdx.x;

    cnt[tid] = 0; cnt[tid + 256] = 0;
    __syncthreads();

    int e0 = buk_off[b];
    int e1 = buk_off[b + 1];
    int nE = e1 - e0;
    bool inlds = (nE <= FCAP);

    if (inlds) {
        for (int e = e0 + tid; e < e1; e += 256) {
            int p = pairs_p[e];
            stage[e - e0] = p;
            atomicAdd(&cnt[P_LOC(p)], 1);
        }
    } else {
        for (int e = e0 + tid; e < e1; e += 256)
            atomicAdd(&cnt[P_LOC(pairs_p[e])], 1);
    }
    __syncthreads();

    int c0 = cnt[2 * tid], c1 = cnt[2 * tid + 1];
    int p = c0 + c1;
    psc[tid] = p;
    __syncthreads();
    for (int s = 1; s < 256; s <<= 1) {
        int add = (tid >= s) ? psc[tid - s] : 0;
        __syncthreads();
        psc[tid] += add;
        __syncthreads();
    }
    int excl = psc[tid] - p;
    int g0 = e0 + excl;
    int g1 = g0 + c0;
    cur[2 * tid] = g0;
    cur[2 * tid + 1] = g1;
    if (2 * tid < nn) {
        row_ptr[node0 + 2 * tid] = g0;
        dinv[node0 + 2 * tid] = 1.0f / sqrtf((float)(c0 + 1));
    }
    if (2 * tid + 1 < nn) {
        row_ptr[node0 + 2 * tid + 1] = g1;
        dinv[node0 + 2 * tid + 1] = 1.0f / sqrtf((float)(c1 + 1));
    }
    if (b == NBUK - 1 && tid == 0) row_ptr[N_NODES] = N_EDGES;
    __syncthreads();

    if (inlds) {
        for (int i = tid; i < nE; i += 256) {
            int pr = stage[i];
            int pos = atomicAdd(&cur[P_LOC(pr)], 1);
            csr_src[pos] = P_SRC(pr);
        }
    } else {
        for (int e = e0 + tid; e < e1; e += 256) {
            int pr = pairs_p[e];
            int pos = atomicAdd(&cur[P_LOC(pr)], 1);
            csr_src[pos] = P_SRC(pr);
        }
    }
}

// ---------------- register-tiled GEMM 1: hws_h = fp16((x @ W1) * dinv[row]) ----------------

__global__ __launch_bounds__(256) void gemm1_tiled_k(const float* __restrict__ x,
                                                     const float* __restrict__ W,
                                                     const float* __restrict__ dinv,
                                                     __half* __restrict__ hws_h) {
    __shared__ float Ws[64][64];
    __shared__ float xt[64][68];
    int tid = threadIdx.x;
    int row0 = blockIdx.x * TM;
    int rgrp4 = (tid >> 4) * 4;
    int cgrp4 = (tid & 15) * 4;

    float acc[4][4];
    #pragma unroll
    for (int r = 0; r < 4; ++r)
        #pragma unroll
        for (int c = 0; c < 4; ++c) acc[r][c] = 0.0f;

    for (int k0 = 0; k0 < IN_FEAT; k0 += 64) {
        #pragma unroll
        for (int i = 0; i < 4; ++i) {
            int f4 = tid + i * 256;
            int kk = f4 >> 4, c4 = (f4 & 15) * 4;
            *(float4*)&Ws[kk][c4] = *(const float4*)&W[(size_t)(k0 + kk) * HIDDEN + c4];
        }
        #pragma unroll
        for (int i = 0; i < 4; ++i) {
            int f4 = tid + i * 256;
            int rr = f4 >> 4, kq = (f4 & 15) * 4;
            int row = row0 + rr;
            if (row >= N_NODES) row = N_NODES - 1;
            float4 v = *(const float4*)&x[(size_t)row * IN_FEAT + k0 + kq];
            xt[kq + 0][rr] = v.x; xt[kq + 1][rr] = v.y;
            xt[kq + 2][rr] = v.z; xt[kq + 3][rr] = v.w;
        }
        __syncthreads();

        #pragma unroll 16
        for (int kk = 0; kk < 64; ++kk) {
            float4 a = *(const float4*)&xt[kk][rgrp4];
            float4 b = *(const float4*)&Ws[kk][cgrp4];
            acc[0][0] += a.x * b.x; acc[0][1] += a.x * b.y; acc[0][2] += a.x * b.z; acc[0][3] += a.x * b.w;
            acc[1][0] += a.y * b.x; acc[1][1] += a.y * b.y; acc[1][2] += a.y * b.z; acc[1][3] += a.y * b.w;
            acc[2][0] += a.z * b.x; acc[2][1] += a.z * b.y; acc[2][2] += a.z * b.z; acc[2][3] += a.z * b.w;
            acc[3][0] += a.w * b.x; acc[3][1] += a.w * b.y; acc[3][2] += a.w * b.z; acc[3][3] += a.w * b.w;
        }
        __syncthreads();
    }

    #pragma unroll
    for (int r = 0; r < 4; ++r) {
        int row = row0 + rgrp4 + r;
        if (row < N_NODES) {
            float dn = dinv[row];
            __half2* ph = (__half2*)&hws_h[(size_t)row * HIDDEN + cgrp4];
            ph[0] = __floats2half2_rn(acc[r][0] * dn, acc[r][1] * dn);
            ph[1] = __floats2half2_rn(acc[r][2] * dn, acc[r][3] * dn);
        }
    }
}

// ---------------- register-tiled GEMM 2: hws_h = fp16((relu(agg) @ W2) * dinv[row]) ----------------

__global__ __launch_bounds__(256) void gemm2_tiled_k(const float* __restrict__ agg,
                                                     const float* __restrict__ W,
                                                     const float* __restrict__ dinv,
                                                     __half* __restrict__ hws_h) {
    __shared__ float Ws[64][64];
    __shared__ float xt[64][68];
    int tid = threadIdx.x;
    int row0 = blockIdx.x * TM;
    int rgrp4 = (tid >> 4) * 4;
    int cgrp4 = (tid & 15) * 4;

    #pragma unroll
    for (int i = 0; i < 4; ++i) {
        int f4 = tid + i * 256;
        int kk = f4 >> 4, c4 = (f4 & 15) * 4;
        *(float4*)&Ws[kk][c4] = *(const float4*)&W[(size_t)kk * HIDDEN + c4];
    }
    #pragma unroll
    for (int i = 0; i < 4; ++i) {
        int f4 = tid + i * 256;
        int rr = f4 >> 4, kq = (f4 & 15) * 4;
        int row = row0 + rr;
        if (row >= N_NODES) row = N_NODES - 1;
        float4 v = *(const float4*)&agg[(size_t)row * HIDDEN + kq];
        xt[kq + 0][rr] = fmaxf(v.x, 0.f); xt[kq + 1][rr] = fmaxf(v.y, 0.f);
        xt[kq + 2][rr] = fmaxf(v.z, 0.f); xt[kq + 3][rr] = fmaxf(v.w, 0.f);
    }
    __syncthreads();

    float acc[4][4];
    #pragma unroll
    for (int r = 0; r < 4; ++r)
        #pragma unroll
        for (int c = 0; c < 4; ++c) acc[r][c] = 0.0f;

    #pragma unroll 16
    for (int kk = 0; kk < 64; ++kk) {
        float4 a = *(const float4*)&xt[kk][rgrp4];
        float4 b = *(const float4*)&Ws[kk][cgrp4];
        acc[0][0] += a.x * b.x; acc[0][1] += a.x * b.y; acc[0][2] += a.x * b.z; acc[0][3] += a.x * b.w;
        acc[1][0] += a.y * b.x; acc[1][1] += a.y * b.y; acc[1][2] += a.y * b.z; acc[1][3] += a.y * b.w;
        acc[2][0] += a.z * b.x; acc[2][1] += a.z * b.y; acc[2][2] += a.z * b.z; acc[2][3] += a.z * b.w;
        acc[3][0] += a.w * b.x; acc[3][1] += a.w * b.y; acc[3][2] += a.w * b.z; acc[3][3] += a.w * b.w;
    }

    #pragma unroll
    for (int r = 0; r < 4; ++r) {
        int row = row0 + rgrp4 + r;
        if (row < N_NODES) {
            float dn = dinv[row];
            __half2* ph = (__half2*)&hws_h[(size_t)row * HIDDEN + cgrp4];
            ph[0] = __floats2half2_rn(acc[r][0] * dn, acc[r][1] * dn);
            ph[1] = __floats2half2_rn(acc[r][2] * dn, acc[r][3] * dn);
        }
    }
}

// ---------------- CSR pull (layer 1): agg[d] = b + dinv[d]*(hws[d] + sum_in hws[s]) ----------------
// one wave per node, lane = channel, fp16 rows, uniform-base gathers,
// 16-wide gather window (A/B-verified optimum; 32-wide regressed: service-
// rate wall, not latency).

#define PULL_BODY(OUT_STMT)                                                  \
    int start = __builtin_amdgcn_readfirstlane(row_ptr[node]);               \
    int end   = __builtin_amdgcn_readfirstlane(row_ptr[node + 1]);           \
    const __half* __restrict__ selfrow = hws_h + ((size_t)node << 6);        \
    float blane = b[lane];                                                   \
    float a0 = __half2float(selfrow[lane]);                                  \
    float dn = dinv[node];                                                   \
    float a1 = 0.f, a2 = 0.f, a3 = 0.f, a4 = 0.f, a5 = 0.f, a6 = 0.f, a7 = 0.f; \
    int base = start;                                                        \
    while (base < end) {                                                     \
        int rem = end - base;                                                \
        int ci = base + lane;                                                \
        int lastci = end - 1;                                                \
        if (ci > lastci) ci = lastci;                                        \
        int idxv = csr_src[ci];                                              \
        int nch = rem < 64 ? rem : 64;                                       \
        for (int j = 0; j < nch; j += 16) {                                  \
            _Pragma("unroll")                                                \
            for (int k = 0; k < 16; ++k) {                                   \
                int jj = j + k;                                              \
                int s = __builtin_amdgcn_readlane(idxv, jj);                 \
                const __half* __restrict__ row = hws_h + ((size_t)s << 6);   \
                float w = (jj < rem) ? 1.f : 0.f;                            \
                float v = __half2float(row[lane]);                           \
                if (k == 0)      a0 += w * v;                                \
                else if (k == 1) a1 += w * v;                                \
                else if (k == 2) a2 += w * v;                                \
                else if (k == 3) a3 += w * v;                                \
                else if (k == 4) a4 += w * v;                                \
                else if (k == 5) a5 += w * v;                                \
                else if (k == 6) a6 += w * v;                                \
                else if (k == 7) a7 += w * v;                                \
                else if (k == 8)  a0 += w * v;                               \
                else if (k == 9)  a1 += w * v;                               \
                else if (k == 10) a2 += w * v;                               \
                else if (k == 11) a3 += w * v;                               \
                else if (k == 12) a4 += w * v;                               \
                else if (k == 13) a5 += w * v;                               \
                else if (k == 14) a6 += w * v;                               \
                else              a7 += w * v;                               \
            }                                                                \
        }                                                                    \
        base += 64;                                                          \
    }                                                                        \
    float sum = ((a0 + a1) + (a2 + a3)) + ((a4 + a5) + (a6 + a7));           \
    float val = blane + dn * sum;                                            \
    OUT_STMT

__global__ __launch_bounds__(256) void pull_k(const int* __restrict__ row_ptr,
                                              const int* __restrict__ csr_src,
                                              const float* __restrict__ dinv,
                                              const __half* __restrict__ hws_h,
                                              const float* __restrict__ b,
                                              float* __restrict__ agg) {
    int node = __builtin_amdgcn_readfirstlane((blockIdx.x * 256 + threadIdx.x) >> 6);
    int lane = threadIdx.x & 63;
    if (node >= N_NODES) return;
    PULL_BODY({ float* __restrict__ outrow = agg + ((size_t)node << 6);
                outrow[lane] = val; })
}

// ---------------- fused pull2 + classifier head ----------------
// pull computes agg[node][lane] in a register -> relu -> LDS -> 64x16 head
// GEMM per block (4 nodes). Deletes final_k (25.6MB R + 6.4MB W + a launch)
// and shrinks this kernel's write from 25.6MB (agg) to 6.4MB (out).
// Grid is exactly N_NODES/4 blocks (100000%4==0): no tail, barrier-safe.

__global__ __launch_bounds__(256) void pull_head_k(const int* __restrict__ row_ptr,
                                                   const int* __restrict__ csr_src,
                                                   const float* __restrict__ dinv,
                                                   const __half* __restrict__ hws_h,
                                                   const float* __restrict__ b,
                                                   const float* __restrict__ Wl,
                                                   const float* __restrict__ bl,
                                                   float* __restrict__ out) {
    __shared__ float hs[4][65];
    __shared__ float Wls[HIDDEN * N_CLASSES];
    __shared__ float bls[N_CLASSES];
    int tid = threadIdx.x;
    int wid = tid >> 6;
    int lane = tid & 63;
    int node = __builtin_amdgcn_readfirstlane(blockIdx.x * 4 + wid);

    // stage head weights (1024 floats: one float4 per thread) + bias
    ((float4*)Wls)[tid] = ((const float4*)Wl)[tid];
    if (tid < N_CLASSES) bls[tid] = bl[tid];

    PULL_BODY({ hs[wid][lane] = fmaxf(val, 0.0f); })

    __syncthreads();
    if (tid < 64) {
        int r = tid >> 4, col = tid & 15;
        float acc = bls[col];
        #pragma unroll
        for (int k = 0; k < HIDDEN; ++k)
            acc += hs[r][k] * Wls[k * N_CLASSES + col];
        out[(size_t)(blockIdx.x * 4 + r) * N_CLASSES + col] = acc;
    }
}

// ---------------- launch ----------------

extern "C" void kernel_launch(void* const* d_in, const int* in_sizes, int n_in,
                              void* d_out, int out_size, void* d_ws, size_t ws_size,
                              hipStream_t stream) {
    const float* x  = (const float*)d_in[0];
    const int*   ei = (const int*)d_in[1];
    const float* W1 = (const float*)d_in[2];
    const float* b1 = (const float*)d_in[3];
    const float* W2 = (const float*)d_in[4];
    const float* b2 = (const float*)d_in[5];
    const float* Wl = (const float*)d_in[6];
    const float* bl = (const float*)d_in[7];
    float* out = (float*)d_out;

    const int* src = ei;
    const int* dst = ei + N_EDGES;

    __half* hws_h  = (__half*)d_ws;                              // N*64 halves (12.8 MB)
    float* agg     = (float*)(hws_h + (size_t)N_NODES * HIDDEN); // N*64 floats (25.6 MB)
    int*   pairs_p = (int*)agg;                                  // packed edges alias agg (dead before pull1 writes agg)
    int*   csr_src = (int*)(agg + (size_t)N_NODES * HIDDEN);     // E
    float* dinv    = (float*)(csr_src + N_EDGES);                // N
    int*   row_ptr = (int*)(dinv + N_NODES);                     // N+4
    int*   buk_cnt = row_ptr + N_NODES + 4;                      // 200 (legacy slot)
    int*   buk_off = buk_cnt + 200;                              // 200
    int*   coltot  = buk_off + 200;                              // 200
    // 391x196 count/colpre matrix aliases csr_src (csr_src written later by fine2)
    int*   blk_cnt = csr_src;

    // --- CSR build (deterministic, atomic-free partition) ---
    count_k<<<NCB, 256, 0, stream>>>(dst, blk_cnt);
    colscan_k<<<NBUK, 512, 0, stream>>>(blk_cnt, coltot);
    bukoff_k<<<1, 256, 0, stream>>>(coltot, buk_off);
    place_k<<<NCB, 256, 0, stream>>>(src, dst, blk_cnt, buk_off, pairs_p);
    fine2_k<<<NBUK, 256, 0, stream>>>(pairs_p, buk_off, csr_src, row_ptr, dinv);

    // --- layer 1 ---
    gemm1_tiled_k<<<GBLK, 256, 0, stream>>>(x, W1, dinv, hws_h);
    pull_k<<<(N_NODES * 64 + 255) / 256, 256, 0, stream>>>(row_ptr, csr_src, dinv,
                                                           hws_h, b1, agg);

    // --- layer 2 (+ fused classifier head) ---
    gemm2_tiled_k<<<GBLK, 256, 0, stream>>>(agg, W2, dinv, hws_h);
    pull_head_k<<<N_NODES / 4, 256, 0, stream>>>(row_ptr, csr_src, dinv,
                                                 hws_h, b2, Wl, bl, out);
}